// Round 9
// baseline (286.690 us; speedup 1.0000x reference)
//
#include <hip/hip_runtime.h>
#include <hip/hip_bf16.h>
#include <cstdint>
#include <cstddef>

#define DEVI static __device__ __forceinline__

typedef unsigned short u16;
typedef unsigned int u32;
typedef __bf16 bf16_t;
typedef __bf16 bf16x8 __attribute__((ext_vector_type(8)));
typedef float f32x4 __attribute__((ext_vector_type(4)));
typedef float f32x16 __attribute__((ext_vector_type(16)));

union U16x8 { uint4 u; bf16x8 v; };
union PU { u32 w[4]; bf16x8 v; };

// 0.125 (1/sqrt(64)) * log2(e): folded into Wq/bq so scores are log2-scaled.
#define QSCALE 0.1803368801111204f

DEVI void gload_lds16(const void* g, void* l) {
  __builtin_amdgcn_global_load_lds((const __attribute__((address_space(1))) void*)g,
                                   (__attribute__((address_space(3))) void*)l, 16, 0, 0);
}
DEVI void wait_vmcnt0() { asm volatile("s_waitcnt vmcnt(0)" ::: "memory"); }

DEVI u32 cvt_pk_bf16(float lo, float hi) {
  u32 r;
  asm("v_cvt_pk_bf16_f32 %0, %1, %2" : "=v"(r) : "v"(lo), "v"(hi));
  return r;
}

// exchange: a's high-32-lane slice <-> b's low-32-lane slice
DEVI void permswap(u32& a, u32& b) {
  asm("v_permlane32_swap_b32 %0, %1" : "+v"(a), "+v"(b));
}

DEVI f32x16 mfma32(bf16x8 a, bf16x8 b, f32x16 c) {
  return __builtin_amdgcn_mfma_f32_32x32x16_bf16(a, b, c, 0, 0, 0);
}

// read one swizzled 16B fragment from a [64][128B] K/V tile
DEVI bf16x8 lds_frag(const char* base, int row, int koff, int swz) {
  U16x8 u;
  u.u = *(const uint4*)(base + row * 128 + (koff ^ swz));
  return u.v;
}

// ---------------------------------------------------------------------------
// Transpose + fp32->bf16 convert (with scale): dst[C][R] = (bf16)(src[R][C]*scale)
// ---------------------------------------------------------------------------
__global__ __launch_bounds__(256) void k_transpose_convert(
    const float* __restrict__ src, bf16_t* __restrict__ dst, int R, int C, float scale) {
  int tiles_c = C >> 6;
  int tc = blockIdx.x % tiles_c;
  int tr = blockIdx.x / tiles_c;
  int r0 = tr << 6, c0 = tc << 6;
  __shared__ u16 tile[64][65];
  int t = threadIdx.x;
  #pragma unroll
  for (int p = 0; p < 4; ++p) {
    int idx = t + p * 256;
    int i = idx >> 4, j4 = (idx & 15) * 4;
    float4 f = *(const float4*)(src + (size_t)(r0 + i) * C + c0 + j4);
    tile[i][j4 + 0] = __builtin_bit_cast(u16, (bf16_t)(f.x * scale));
    tile[i][j4 + 1] = __builtin_bit_cast(u16, (bf16_t)(f.y * scale));
    tile[i][j4 + 2] = __builtin_bit_cast(u16, (bf16_t)(f.z * scale));
    tile[i][j4 + 3] = __builtin_bit_cast(u16, (bf16_t)(f.w * scale));
  }
  __syncthreads();
  #pragma unroll
  for (int p = 0; p < 2; ++p) {
    int idx = t + p * 256;
    int j = idx >> 3, i0 = (idx & 7) * 8;
    u16 us[8];
    #pragma unroll
    for (int e = 0; e < 8; ++e) us[e] = tile[i0 + e][j];
    uint4 o;
    o.x = (u32)us[0] | ((u32)us[1] << 16);
    o.y = (u32)us[2] | ((u32)us[3] << 16);
    o.z = (u32)us[4] | ((u32)us[5] << 16);
    o.w = (u32)us[6] | ((u32)us[7] << 16);
    *(uint4*)((u16*)dst + (size_t)(c0 + j) * R + r0 + i0) = o;
  }
}

// ---------------------------------------------------------------------------
// QKV projection GEMM v3: reg-prefetch A (fp32->cvt_pk) and B (bf16) one
// kt ahead; no global_load_lds -> no vmcnt(0) barrier drain; latency hides
// under compute. XCD-chunked tile map: xcd=bid&7 owns tile_m in [8x,8x+8)
// for all 8 tile_n -> A panel reuse is L2-local. BM=BN=128, BK=64, 256 thr.
// grid = 3*512.
// ---------------------------------------------------------------------------
__global__ __launch_bounds__(256) void k_proj_gemm(
    const float* __restrict__ Aq, const float* __restrict__ Ak, const float* __restrict__ Av,
    const bf16_t* __restrict__ WqT, const bf16_t* __restrict__ WkT, const bf16_t* __restrict__ WvT,
    const float* __restrict__ bq, const float* __restrict__ bk, const float* __restrict__ bv,
    bf16_t* __restrict__ qh, bf16_t* __restrict__ kh, bf16_t* __restrict__ vh) {
  const int bid = blockIdx.x;
  const int which = bid >> 9;
  const int b9 = bid & 511;
  const int xcd = b9 & 7, j = b9 >> 3;
  const int tile_m = xcd * 8 + (j >> 3);
  const int tile_n = j & 7;
  const float* A    = which == 0 ? Aq : which == 1 ? Ak : Av;
  const bf16_t* WT  = which == 0 ? WqT : which == 1 ? WkT : WvT;
  const float* bias = which == 0 ? bq : which == 1 ? bk : bv;
  const float bscale = which == 0 ? QSCALE : 1.0f;
  bf16_t* dst       = which == 0 ? qh : which == 1 ? kh : vh;

  const int t = threadIdx.x;
  const int l = t & 63;
  const int w = t >> 6;
  const int wm = w >> 1, wn = w & 1;
  const int c = l & 15, g = l >> 4;
  const int row0 = tile_m << 7;
  const int n0 = tile_n << 7;

  __shared__ __align__(16) char As[128 * 64 * 2];
  __shared__ __align__(16) char Bs[128 * 64 * 2];

  f32x4 acc[4][4];
  #pragma unroll
  for (int i = 0; i < 4; ++i)
    #pragma unroll
    for (int jj = 0; jj < 4; ++jj) acc[i][jj] = (f32x4){0.f, 0.f, 0.f, 0.f};

  // A map: row = p*16 + (t>>4), fp32 col4 = (t&15)*4. (p*16)&7==0 -> swizzle
  // constant per thread.
  const int arow_b = t >> 4, ac4 = t & 15;
  const float* agbase = A + (size_t)(row0 + arow_b) * 1024 + ac4 * 4;
  char* aldst = As + arow_b * 128 + (((ac4 >> 1) ^ (arow_b & 7)) << 4) + (ac4 & 1) * 8;

  // B map: row = p*32 + (t>>3), chunk chs = t&7. (p*32)&7==0 -> swizzle const.
  const int brow_b = t >> 3, bchs = t & 7;
  const u16* bgbase = (const u16*)WT + (size_t)(n0 + brow_b) * 1024 + bchs * 8;
  char* bldst = Bs + brow_b * 128 + ((bchs ^ (brow_b & 7)) << 4);

  float4 fa0[8], fa1[8];
  uint4 fb0[4], fb1[4];

  auto loadA = [&](int kt, float4* f) {
    const float* ap = agbase + kt * 64;
    #pragma unroll
    for (int p = 0; p < 8; ++p) f[p] = *(const float4*)(ap + (size_t)p * 16384);
  };
  auto loadB = [&](int kt, uint4* u) {
    const u16* bp = bgbase + kt * 64;
    #pragma unroll
    for (int p = 0; p < 4; ++p) u[p] = *(const uint4*)(bp + (size_t)p * 32768);
  };
  auto storeA = [&](const float4* f) {
    #pragma unroll
    for (int p = 0; p < 8; ++p) {
      uint2 o;
      o.x = cvt_pk_bf16(f[p].x, f[p].y);
      o.y = cvt_pk_bf16(f[p].z, f[p].w);
      *(uint2*)(aldst + p * 2048) = o;
    }
  };
  auto storeB = [&](const uint4* u) {
    #pragma unroll
    for (int p = 0; p < 4; ++p) *(uint4*)(bldst + p * 4096) = u[p];
  };
  auto compute = [&]() {
    #pragma unroll
    for (int kk = 0; kk < 2; ++kk) {
      bf16x8 af[4], bfr[4];
      #pragma unroll
      for (int mi = 0; mi < 4; ++mi) {
        int row = wm * 64 + mi * 16 + c;
        U16x8 u; u.u = *(const uint4*)(As + row * 128 + ((kk * 64 + g * 16) ^ ((c & 7) << 4)));
        af[mi] = u.v;
      }
      #pragma unroll
      for (int ni = 0; ni < 4; ++ni) {
        int row = wn * 64 + ni * 16 + c;
        U16x8 u; u.u = *(const uint4*)(Bs + row * 128 + ((kk * 64 + g * 16) ^ ((c & 7) << 4)));
        bfr[ni] = u.v;
      }
      #pragma unroll
      for (int mi = 0; mi < 4; ++mi)
        #pragma unroll
        for (int ni = 0; ni < 4; ++ni)
          acc[mi][ni] = __builtin_amdgcn_mfma_f32_16x16x32_bf16(af[mi], bfr[ni], acc[mi][ni], 0, 0, 0);
    }
  };

  loadA(0, fa0); loadB(0, fb0);
  for (int i = 0; i < 8; ++i) {
    __syncthreads();                     // LDS readers of previous tile done
    storeA(fa0); storeB(fb0);            // waits only on loads from last segment
    loadA(2 * i + 1, fa1); loadB(2 * i + 1, fb1);
    __syncthreads();
    compute();                           // kt = 2i
    __syncthreads();
    storeA(fa1); storeB(fb1);
    if (i < 7) { loadA(2 * i + 2, fa0); loadB(2 * i + 2, fb0); }
    __syncthreads();
    compute();                           // kt = 2i+1
  }

  u16* dd = (u16*)dst;
  #pragma unroll
  for (int ni = 0; ni < 4; ++ni) {
    int col = n0 + wn * 64 + ni * 16 + c;
    float bb = bias[col] * bscale;
    int h = col >> 6, d = col & 63;
    #pragma unroll
    for (int mi = 0; mi < 4; ++mi) {
      #pragma unroll
      for (int r = 0; r < 4; ++r) {
        int rowg = row0 + wm * 64 + mi * 16 + g * 4 + r;
        int b = rowg >> 11, s = rowg & 2047;
        float vv = acc[mi][ni][r] + bb;
        size_t idx = (((size_t)b * 16 + h) * 2048 + s) * 64 + d;
        dd[idx] = __builtin_bit_cast(u16, (bf16_t)vv);
      }
    }
  }
}

// ---------------------------------------------------------------------------
// V transpose: vh (B,H,S,Dk) -> vT (B,H,Dk,S). 64x64 tiles. grid = 64*32.
// ---------------------------------------------------------------------------
__global__ __launch_bounds__(256) void k_transpose_v(
    const bf16_t* __restrict__ vh, bf16_t* __restrict__ vT) {
  int bh = blockIdx.x >> 5, st = blockIdx.x & 31;
  int s0 = st << 6;
  __shared__ __align__(16) u16 tile[64][72];
  int t = threadIdx.x;
  const u16* src = (const u16*)vh + ((size_t)bh * 2048 + s0) * 64;
  #pragma unroll
  for (int p = 0; p < 2; ++p) {
    int idx = t + p * 256;
    int s = idx >> 3, d0 = (idx & 7) * 8;
    uint4 v = *(const uint4*)(src + s * 64 + d0);
    *(uint4*)(&tile[s][d0]) = v;
  }
  __syncthreads();
  u16* dst = (u16*)vT + (size_t)bh * 64 * 2048 + s0;
  #pragma unroll
  for (int p = 0; p < 2; ++p) {
    int idx = t + p * 256;
    int d = idx >> 3, s1 = (idx & 7) * 8;
    u16 us[8];
    #pragma unroll
    for (int e = 0; e < 8; ++e) us[e] = tile[s1 + e][d];
    uint4 o;
    o.x = (u32)us[0] | ((u32)us[1] << 16);
    o.y = (u32)us[2] | ((u32)us[3] << 16);
    o.z = (u32)us[4] | ((u32)us[5] << 16);
    o.w = (u32)us[6] | ((u32)us[7] << 16);
    *(uint4*)(dst + (size_t)d * 2048 + s1) = o;
  }
}

// ---------------------------------------------------------------------------
// Flash attention v7: 32x32x16 MFMA, P in-register via cvt_pk +
// permlane32_swap, double-buffered K/V with issue-early staging.
// grid = 1024 (XCD swizzle); 256 thr = 4 waves, wave owns 32 q rows.
// ---------------------------------------------------------------------------
__global__ __launch_bounds__(256, 4) void k_attn(
    const bf16_t* __restrict__ qh, const bf16_t* __restrict__ kh,
    const bf16_t* __restrict__ vT, bf16_t* __restrict__ ctx) {
  const int bid = blockIdx.x;
  const int bx = ((bid & 7) << 7) | (bid >> 3);   // XCD swizzle: 1024 = 8*128
  const int bh = bx >> 4;
  const int qt = bx & 15;
  const int q0 = qt << 7;                          // 128 q rows per block
  const int t = threadIdx.x, l = t & 63, w = t >> 6;  // w 0..3
  const int q = l & 31;                            // lane's q (and frag row)
  const int hi = l >> 5;                           // k-subgroup
  const int swz = (q & 7) << 4;                    // frag-read XOR

  __shared__ __align__(16) char Ks[2][64 * 128];
  __shared__ __align__(16) char Vs[2][64 * 128];
  __shared__ __align__(16) float Dn[4][32];

  // Q^T B-frags: lane holds Q[q0+w*32+q][ks*16 + hi*8 + j], ks = 0..3
  const u16* qrow = (const u16*)qh + ((size_t)bh * 2048 + q0 + w * 32 + q) * 64;
  bf16x8 qf0, qf1, qf2, qf3;
  {
    U16x8 u;
    u.u = *(const uint4*)(qrow + 0 * 16 + hi * 8); qf0 = u.v;
    u.u = *(const uint4*)(qrow + 1 * 16 + hi * 8); qf1 = u.v;
    u.u = *(const uint4*)(qrow + 2 * 16 + hi * 8); qf2 = u.v;
    u.u = *(const uint4*)(qrow + 3 * 16 + hi * 8); qf3 = u.v;
  }

  const f32x16 z16 = {0.f,0.f,0.f,0.f, 0.f,0.f,0.f,0.f, 0.f,0.f,0.f,0.f, 0.f,0.f,0.f,0.f};
  f32x16 oc0 = z16, oc1 = z16;
  float l_run = 0.f;

  const u16* kbh = (const u16*)kh + (size_t)bh * 2048 * 64;
  const u16* vbh = (const u16*)vT + (size_t)bh * 64 * 2048;

  auto stage = [&](int kvi, int buf) {
    int kbase = kvi << 6;
    #pragma unroll
    for (int cc = 0; cc < 2; ++cc) {
      int slot = w * 128 + cc * 64 + l;
      int row = slot >> 3, chs = slot & 7;
      gload_lds16(kbh + (size_t)(kbase + row) * 64 + ((chs ^ (row & 7)) << 3),
                  Ks[buf] + (w * 128 + cc * 64) * 16);
      gload_lds16(vbh + (size_t)row * 2048 + kbase + ((chs ^ (row & 7)) << 3),
                  Vs[buf] + (w * 128 + cc * 64) * 16);
    }
  };

  stage(0, 0);
  wait_vmcnt0();
  __syncthreads();

  for (int kv = 0; kv < 32; ++kv) {
    const int cur = kv & 1;
    if (kv < 31) stage(kv + 1, cur ^ 1);          // issue-early prefetch
    const char* Kc = Ks[cur];
    const char* Vc = Vs[cur];

    #pragma unroll
    for (int tt = 0; tt < 2; ++tt) {
      // ---- QK^T: S^T[k' = tt*32 + 8qd+4hi+r][q], log2 units ----
      const int arow = tt * 32 + q;
      f32x16 st = z16;
      __builtin_amdgcn_s_setprio(1);
      st = mfma32(lds_frag(Kc, arow, 0 * 32 + hi * 16, swz), qf0, st);
      st = mfma32(lds_frag(Kc, arow, 1 * 32 + hi * 16, swz), qf1, st);
      st = mfma32(lds_frag(Kc, arow, 2 * 32 + hi * 16, swz), qf2, st);
      st = mfma32(lds_frag(Kc, arow, 3 * 32 + hi * 16, swz), qf3, st);
      __builtin_amdgcn_s_setprio(0);

      // ---- softmax numerators (no max): exp2 + sum ----
      float e[16];
      #pragma unroll
      for (int i = 0; i < 16; ++i) {
        e[i] = __builtin_amdgcn_exp2f(st[i]);
        l_run += e[i];
      }

      // ---- P -> A-frags in-register: cvt_pk + permlane32_swap ----
      #pragma unroll
      for (int cc = 0; cc < 2; ++cc) {
        u32 a  = cvt_pk_bf16(e[8 * cc + 0], e[8 * cc + 1]);
        u32 b  = cvt_pk_bf16(e[8 * cc + 4], e[8 * cc + 5]);
        u32 c2 = cvt_pk_bf16(e[8 * cc + 2], e[8 * cc + 3]);
        u32 d  = cvt_pk_bf16(e[8 * cc + 6], e[8 * cc + 7]);
        permswap(a, b);
        permswap(c2, d);
        PU pu;
        pu.w[0] = a; pu.w[1] = c2; pu.w[2] = b; pu.w[3] = d;
        const int ks = tt * 2 + cc;                // global 16-k chunk
        __builtin_amdgcn_s_setprio(1);
        oc0 = mfma32(pu.v, lds_frag(Vc, q,      ks * 32 + hi * 16, swz), oc0);
        oc1 = mfma32(pu.v, lds_frag(Vc, 32 + q, ks * 32 + hi * 16, swz), oc1);
        __builtin_amdgcn_s_setprio(0);
      }
    }
    wait_vmcnt0();      // next tile's staging landed
    __syncthreads();
  }

  // ---- epilogue: denom broadcast, normalize, store ctx (B,S,E) bf16 ----
  l_run += __shfl_xor(l_run, 32);     // lanes q and q+32 hold complementary k
  Dn[w][q] = 1.f / l_run;
  __syncthreads();

  const int b = bh >> 4, hh = bh & 15;
  u16* cb = (u16*)ctx;
  #pragma unroll
  for (int qd = 0; qd < 4; ++qd) {
    float4 dv = *(const float4*)&Dn[w][qd * 8 + hi * 4];
    #pragma unroll
    for (int r = 0; r < 4; ++r) {
      float inv = (&dv.x)[r];
      int qrow_g = q0 + w * 32 + qd * 8 + hi * 4 + r;
      size_t base = ((size_t)b * 2048 + qrow_g) * 1024 + hh * 64;
      float v0 = oc0[qd * 4 + r] * inv;
      float v1 = oc1[qd * 4 + r] * inv;
      cb[base + q]      = __builtin_bit_cast(u16, (bf16_t)v0);
      cb[base + 32 + q] = __builtin_bit_cast(u16, (bf16_t)v1);
    }
  }
}

// ---------------------------------------------------------------------------
// Output projection: out[8192,64] = ctx(bf16) @ Wo + bo (fp32 out). grid = 64.
// ---------------------------------------------------------------------------
__global__ __launch_bounds__(256) void k_out_gemm(
    const bf16_t* __restrict__ ctx, const bf16_t* __restrict__ WoT,
    const float* __restrict__ bo, float* __restrict__ out) {
  int tile_m = blockIdx.x;
  const int t = threadIdx.x, l = t & 63, w = t >> 6;
  const int wm = w >> 1, wn = w & 1;
  const int c = l & 15, g = l >> 4;
  const int row0 = tile_m << 7;

  __shared__ __align__(16) char As[128 * 64 * 2];
  __shared__ __align__(16) char Bs[64 * 64 * 2];

  f32x4 acc[4][2];
  #pragma unroll
  for (int i = 0; i < 4; ++i)
    #pragma unroll
    for (int j = 0; j < 2; ++j) acc[i][j] = (f32x4){0.f, 0.f, 0.f, 0.f};

  for (int kt = 0; kt < 16; ++kt) {
    __syncthreads();
    #pragma unroll
    for (int cc = 0; cc < 4; ++cc) {
      int slot = w * 256 + cc * 64 + l;
      int row = slot >> 3, chs = slot & 7;
      const bf16_t* src = ctx + (size_t)(row0 + row) * 1024 + kt * 64 + ((chs ^ (row & 7)) << 3);
      gload_lds16(src, As + (w * 256 + cc * 64) * 16);
    }
    #pragma unroll
    for (int cc = 0; cc < 2; ++cc) {
      int slot = w * 128 + cc * 64 + l;
      int row = slot >> 3, chs = slot & 7;
      const bf16_t* src = WoT + (size_t)row * 1024 + kt * 64 + ((chs ^ (row & 7)) << 3);
      gload_lds16(src, Bs + (w * 128 + cc * 64) * 16);
    }
    wait_vmcnt0();
    __syncthreads();
    #pragma unroll
    for (int kk = 0; kk < 2; ++kk) {
      bf16x8 af[4], bfr[2];
      #pragma unroll
      for (int mi = 0; mi < 4; ++mi) {
        int row = wm * 64 + mi * 16 + c;
        U16x8 u; u.u = *(const uint4*)(As + row * 128 + ((kk * 64 + g * 16) ^ ((c & 7) << 4)));
        af[mi] = u.v;
      }
      #pragma unroll
      for (int ni = 0; ni < 2; ++ni) {
        int row = wn * 32 + ni * 16 + c;
        U16x8 u; u.u = *(const uint4*)(Bs + row * 128 + ((kk * 64 + g * 16) ^ ((c & 7) << 4)));
        bfr[ni] = u.v;
      }
      #pragma unroll
      for (int mi = 0; mi < 4; ++mi)
        #pragma unroll
        for (int ni = 0; ni < 2; ++ni)
          acc[mi][ni] = __builtin_amdgcn_mfma_f32_16x16x32_bf16(af[mi], bfr[ni], acc[mi][ni], 0, 0, 0);
    }
  }
  #pragma unroll
  for (int ni = 0; ni < 2; ++ni) {
    int col = wn * 32 + ni * 16 + c;
    float bb = bo[col];
    #pragma unroll
    for (int mi = 0; mi < 4; ++mi) {
      #pragma unroll
      for (int r = 0; r < 4; ++r) {
        int rowg = row0 + wm * 64 + mi * 16 + g * 4 + r;
        out[(size_t)rowg * 64 + col] = acc[mi][ni][r] + bb;
      }
    }
  }
}

// ---------------------------------------------------------------------------
extern "C" void kernel_launch(void* const* d_in, const int* in_sizes, int n_in,
                              void* d_out, int out_size, void* d_ws, size_t ws_size,
                              hipStream_t stream) {
  (void)in_sizes; (void)n_in; (void)out_size; (void)ws_size;
  const float* query = (const float*)d_in[0];
  const float* key_  = (const float*)d_in[1];
  const float* value = (const float*)d_in[2];
  const float* Wq = (const float*)d_in[3];
  const float* bq = (const float*)d_in[4];
  const float* Wk = (const float*)d_in[5];
  const float* bk = (const float*)d_in[6];
  const float* Wv = (const float*)d_in[7];
  const float* bv = (const float*)d_in[8];
  const float* Wo = (const float*)d_in[9];
  const float* bo = (const float*)d_in[10];
  float* out = (float*)d_out;

  char* ws = (char*)d_ws;
  bf16_t* WqT = (bf16_t*)(ws + (size_t)0);
  bf16_t* WkT = (bf16_t*)(ws + ((size_t)2 << 20));
  bf16_t* WvT = (bf16_t*)(ws + ((size_t)4 << 20));
  bf16_t* WoT = (bf16_t*)(ws + ((size_t)6 << 20));
  bf16_t* qhd = (bf16_t*)(ws + ((size_t)8 << 20));
  bf16_t* khd = (bf16_t*)(ws + ((size_t)24 << 20));
  bf16_t* vhd = (bf16_t*)(ws + ((size_t)40 << 20));
  bf16_t* vT  = (bf16_t*)(ws + ((size_t)56 << 20));
  bf16_t* ctx = (bf16_t*)(ws + ((size_t)72 << 20));

  // weight transposes (+ QSCALE folded into Wq)
  k_transpose_convert<<<256, 256, 0, stream>>>(Wq, WqT, 1024, 1024, QSCALE);
  k_transpose_convert<<<256, 256, 0, stream>>>(Wk, WkT, 1024, 1024, 1.0f);
  k_transpose_convert<<<256, 256, 0, stream>>>(Wv, WvT, 1024, 1024, 1.0f);
  k_transpose_convert<<<16, 256, 0, stream>>>(Wo, WoT, 1024, 64, 1.0f);

  k_proj_gemm<<<1536, 256, 0, stream>>>(query, key_, value, WqT, WkT, WvT,
                                        bq, bk, bv, qhd, khd, vhd);
  k_transpose_v<<<2048, 256, 0, stream>>>(vhd, vT);
  k_attn<<<1024, 256, 0, stream>>>(qhd, khd, vT, ctx);
  k_out_gemm<<<64, 256, 0, stream>>>(ctx, WoT, bo, out);
}

// Round 10
// 262.343 us; speedup vs baseline: 1.0928x; 1.0928x over previous
//
#include <hip/hip_runtime.h>
#include <hip/hip_bf16.h>
#include <cstdint>
#include <cstddef>

#define DEVI static __device__ __forceinline__

typedef unsigned short u16;
typedef unsigned int u32;
typedef __bf16 bf16_t;
typedef __bf16 bf16x8 __attribute__((ext_vector_type(8)));
typedef float f32x4 __attribute__((ext_vector_type(4)));
typedef float f32x16 __attribute__((ext_vector_type(16)));

union U16x8 { uint4 u; bf16x8 v; };
union PU { u32 w[4]; bf16x8 v; };

// 0.125 (1/sqrt(64)) * log2(e): folded into Wq/bq so scores are log2-scaled.
#define QSCALE 0.1803368801111204f

DEVI void gload_lds16(const void* g, void* l) {
  __builtin_amdgcn_global_load_lds((const __attribute__((address_space(1))) void*)g,
                                   (__attribute__((address_space(3))) void*)l, 16, 0, 0);
}
DEVI void wait_vmcnt0() { asm volatile("s_waitcnt vmcnt(0)" ::: "memory"); }

DEVI u32 cvt_pk_bf16(float lo, float hi) {
  u32 r;
  asm("v_cvt_pk_bf16_f32 %0, %1, %2" : "=v"(r) : "v"(lo), "v"(hi));
  return r;
}

// exchange: a's high-32-lane slice <-> b's low-32-lane slice
DEVI void permswap(u32& a, u32& b) {
  asm("v_permlane32_swap_b32 %0, %1" : "+v"(a), "+v"(b));
}

DEVI f32x16 mfma32(bf16x8 a, bf16x8 b, f32x16 c) {
  return __builtin_amdgcn_mfma_f32_32x32x16_bf16(a, b, c, 0, 0, 0);
}

// read one swizzled 16B fragment from a [64][128B] K/V tile
DEVI bf16x8 lds_frag(const char* base, int row, int koff, int swz) {
  U16x8 u;
  u.u = *(const uint4*)(base + row * 128 + (koff ^ swz));
  return u.v;
}

// ---------------------------------------------------------------------------
// Transpose + fp32->bf16 convert (with scale): dst[C][R] = (bf16)(src[R][C]*scale)
// ---------------------------------------------------------------------------
__global__ __launch_bounds__(256) void k_transpose_convert(
    const float* __restrict__ src, bf16_t* __restrict__ dst, int R, int C, float scale) {
  int tiles_c = C >> 6;
  int tc = blockIdx.x % tiles_c;
  int tr = blockIdx.x / tiles_c;
  int r0 = tr << 6, c0 = tc << 6;
  __shared__ u16 tile[64][65];
  int t = threadIdx.x;
  #pragma unroll
  for (int p = 0; p < 4; ++p) {
    int idx = t + p * 256;
    int i = idx >> 4, j4 = (idx & 15) * 4;
    float4 f = *(const float4*)(src + (size_t)(r0 + i) * C + c0 + j4);
    tile[i][j4 + 0] = __builtin_bit_cast(u16, (bf16_t)(f.x * scale));
    tile[i][j4 + 1] = __builtin_bit_cast(u16, (bf16_t)(f.y * scale));
    tile[i][j4 + 2] = __builtin_bit_cast(u16, (bf16_t)(f.z * scale));
    tile[i][j4 + 3] = __builtin_bit_cast(u16, (bf16_t)(f.w * scale));
  }
  __syncthreads();
  #pragma unroll
  for (int p = 0; p < 2; ++p) {
    int idx = t + p * 256;
    int j = idx >> 3, i0 = (idx & 7) * 8;
    u16 us[8];
    #pragma unroll
    for (int e = 0; e < 8; ++e) us[e] = tile[i0 + e][j];
    uint4 o;
    o.x = (u32)us[0] | ((u32)us[1] << 16);
    o.y = (u32)us[2] | ((u32)us[3] << 16);
    o.z = (u32)us[4] | ((u32)us[5] << 16);
    o.w = (u32)us[6] | ((u32)us[7] << 16);
    *(uint4*)((u16*)dst + (size_t)(c0 + j) * R + r0 + i0) = o;
  }
}

// ---------------------------------------------------------------------------
// QKV projection GEMM v4: single-set reg-prefetch one kt ahead, fully inline
// (no pointer-param lambdas -> no scratch spill; round-9 lesson). Schedule:
// issue loads(kt+1) -> compute(kt) -> barrier -> store regs->LDS -> barrier.
// No global_load_lds => no vmcnt(0) drain at barriers. BM=BN=128, BK=64.
// grid = 3*512.
// ---------------------------------------------------------------------------
__global__ __launch_bounds__(256) void k_proj_gemm(
    const float* __restrict__ Aq, const float* __restrict__ Ak, const float* __restrict__ Av,
    const bf16_t* __restrict__ WqT, const bf16_t* __restrict__ WkT, const bf16_t* __restrict__ WvT,
    const float* __restrict__ bq, const float* __restrict__ bk, const float* __restrict__ bv,
    bf16_t* __restrict__ qh, bf16_t* __restrict__ kh, bf16_t* __restrict__ vh) {
  const int bx = blockIdx.x;
  const int which = bx >> 9;
  const int tt = bx & 511;
  const int tile_m = tt & 63;
  const int tile_n = tt >> 6;
  const float* A    = which == 0 ? Aq : which == 1 ? Ak : Av;
  const bf16_t* WT  = which == 0 ? WqT : which == 1 ? WkT : WvT;
  const float* bias = which == 0 ? bq : which == 1 ? bk : bv;
  const float bscale = which == 0 ? QSCALE : 1.0f;
  bf16_t* dst       = which == 0 ? qh : which == 1 ? kh : vh;

  const int t = threadIdx.x;
  const int l = t & 63;
  const int w = t >> 6;
  const int wm = w >> 1, wn = w & 1;
  const int c = l & 15, g = l >> 4;
  const int row0 = tile_m << 7;
  const int n0 = tile_n << 7;

  __shared__ __align__(16) char As[128 * 64 * 2];
  __shared__ __align__(16) char Bs[128 * 64 * 2];

  f32x4 acc[4][4];
  #pragma unroll
  for (int i = 0; i < 4; ++i)
    #pragma unroll
    for (int j = 0; j < 4; ++j) acc[i][j] = (f32x4){0.f, 0.f, 0.f, 0.f};

  // A map: row = p*16 + (t>>4), fp32 col4 = (t&15)*4; (p*16)&7==0 -> swizzle
  // constant per thread. 16 consecutive lanes read 256B bursts (coalesced).
  const int arow_b = t >> 4, ac4 = t & 15;
  const float* agbase = A + (size_t)(row0 + arow_b) * 1024 + ac4 * 4;
  char* aldst = As + arow_b * 128 + (((ac4 >> 1) ^ (arow_b & 7)) << 4) + (ac4 & 1) * 8;

  // B map: row = p*32 + (t>>3), chunk chs = t&7; (p*32)&7==0 -> swizzle const.
  const int brow_b = t >> 3, bchs = t & 7;
  const u16* bgbase = (const u16*)WT + (size_t)(n0 + brow_b) * 1024 + bchs * 8;
  char* bldst = Bs + brow_b * 128 + ((bchs ^ (brow_b & 7)) << 4);

  float4 fa[8];
  uint4 fb[4];

  // ---- prologue: load + store kt=0 ----
  #pragma unroll
  for (int p = 0; p < 8; ++p) fa[p] = *(const float4*)(agbase + (size_t)p * 16384);
  #pragma unroll
  for (int p = 0; p < 4; ++p) fb[p] = *(const uint4*)(bgbase + (size_t)p * 32768);
  #pragma unroll
  for (int p = 0; p < 8; ++p) {
    uint2 o;
    o.x = cvt_pk_bf16(fa[p].x, fa[p].y);
    o.y = cvt_pk_bf16(fa[p].z, fa[p].w);
    *(uint2*)(aldst + p * 2048) = o;
  }
  #pragma unroll
  for (int p = 0; p < 4; ++p) *(uint4*)(bldst + p * 4096) = fb[p];
  __syncthreads();

  for (int kt = 0; kt < 16; ++kt) {
    // ---- issue next tile's loads into regs (cross barriers freely) ----
    if (kt < 15) {
      const float* ap = agbase + (kt + 1) * 64;
      #pragma unroll
      for (int p = 0; p < 8; ++p) fa[p] = *(const float4*)(ap + (size_t)p * 16384);
      const u16* bp = bgbase + (kt + 1) * 64;
      #pragma unroll
      for (int p = 0; p < 4; ++p) fb[p] = *(const uint4*)(bp + (size_t)p * 32768);
    }
    // ---- compute tile kt from LDS (hides load latency) ----
    #pragma unroll
    for (int kk = 0; kk < 2; ++kk) {
      bf16x8 af[4], bfr[4];
      #pragma unroll
      for (int mi = 0; mi < 4; ++mi) {
        int row = wm * 64 + mi * 16 + c;
        U16x8 u; u.u = *(const uint4*)(As + row * 128 + ((kk * 64 + g * 16) ^ ((c & 7) << 4)));
        af[mi] = u.v;
      }
      #pragma unroll
      for (int ni = 0; ni < 4; ++ni) {
        int row = wn * 64 + ni * 16 + c;
        U16x8 u; u.u = *(const uint4*)(Bs + row * 128 + ((kk * 64 + g * 16) ^ ((c & 7) << 4)));
        bfr[ni] = u.v;
      }
      #pragma unroll
      for (int mi = 0; mi < 4; ++mi)
        #pragma unroll
        for (int ni = 0; ni < 4; ++ni)
          acc[mi][ni] = __builtin_amdgcn_mfma_f32_16x16x32_bf16(af[mi], bfr[ni], acc[mi][ni], 0, 0, 0);
    }
    __syncthreads();
    // ---- store prefetched regs -> LDS (waits only on remaining latency) ----
    if (kt < 15) {
      #pragma unroll
      for (int p = 0; p < 8; ++p) {
        uint2 o;
        o.x = cvt_pk_bf16(fa[p].x, fa[p].y);
        o.y = cvt_pk_bf16(fa[p].z, fa[p].w);
        *(uint2*)(aldst + p * 2048) = o;
      }
      #pragma unroll
      for (int p = 0; p < 4; ++p) *(uint4*)(bldst + p * 4096) = fb[p];
      __syncthreads();
    }
  }

  u16* dd = (u16*)dst;
  #pragma unroll
  for (int ni = 0; ni < 4; ++ni) {
    int col = n0 + wn * 64 + ni * 16 + c;
    float bb = bias[col] * bscale;
    int h = col >> 6, d = col & 63;
    #pragma unroll
    for (int mi = 0; mi < 4; ++mi) {
      #pragma unroll
      for (int r = 0; r < 4; ++r) {
        int rowg = row0 + wm * 64 + mi * 16 + g * 4 + r;
        int b = rowg >> 11, s = rowg & 2047;
        float vv = acc[mi][ni][r] + bb;
        size_t idx = (((size_t)b * 16 + h) * 2048 + s) * 64 + d;
        dd[idx] = __builtin_bit_cast(u16, (bf16_t)vv);
      }
    }
  }
}

// ---------------------------------------------------------------------------
// V transpose: vh (B,H,S,Dk) -> vT (B,H,Dk,S). 64x64 tiles. grid = 64*32.
// ---------------------------------------------------------------------------
__global__ __launch_bounds__(256) void k_transpose_v(
    const bf16_t* __restrict__ vh, bf16_t* __restrict__ vT) {
  int bh = blockIdx.x >> 5, st = blockIdx.x & 31;
  int s0 = st << 6;
  __shared__ __align__(16) u16 tile[64][72];
  int t = threadIdx.x;
  const u16* src = (const u16*)vh + ((size_t)bh * 2048 + s0) * 64;
  #pragma unroll
  for (int p = 0; p < 2; ++p) {
    int idx = t + p * 256;
    int s = idx >> 3, d0 = (idx & 7) * 8;
    uint4 v = *(const uint4*)(src + s * 64 + d0);
    *(uint4*)(&tile[s][d0]) = v;
  }
  __syncthreads();
  u16* dst = (u16*)vT + (size_t)bh * 64 * 2048 + s0;
  #pragma unroll
  for (int p = 0; p < 2; ++p) {
    int idx = t + p * 256;
    int d = idx >> 3, s1 = (idx & 7) * 8;
    u16 us[8];
    #pragma unroll
    for (int e = 0; e < 8; ++e) us[e] = tile[s1 + e][d];
    uint4 o;
    o.x = (u32)us[0] | ((u32)us[1] << 16);
    o.y = (u32)us[2] | ((u32)us[3] << 16);
    o.z = (u32)us[4] | ((u32)us[5] << 16);
    o.w = (u32)us[6] | ((u32)us[7] << 16);
    *(uint4*)(dst + (size_t)d * 2048 + s1) = o;
  }
}

// ---------------------------------------------------------------------------
// Flash attention v7: 32x32x16 MFMA, P in-register via cvt_pk +
// permlane32_swap, double-buffered K/V with issue-early staging.
// grid = 1024 (XCD swizzle); 256 thr = 4 waves, wave owns 32 q rows.
// ---------------------------------------------------------------------------
__global__ __launch_bounds__(256, 4) void k_attn(
    const bf16_t* __restrict__ qh, const bf16_t* __restrict__ kh,
    const bf16_t* __restrict__ vT, bf16_t* __restrict__ ctx) {
  const int bid = blockIdx.x;
  const int bx = ((bid & 7) << 7) | (bid >> 3);   // XCD swizzle: 1024 = 8*128
  const int bh = bx >> 4;
  const int qt = bx & 15;
  const int q0 = qt << 7;                          // 128 q rows per block
  const int t = threadIdx.x, l = t & 63, w = t >> 6;  // w 0..3
  const int q = l & 31;                            // lane's q (and frag row)
  const int hi = l >> 5;                           // k-subgroup
  const int swz = (q & 7) << 4;                    // frag-read XOR

  __shared__ __align__(16) char Ks[2][64 * 128];
  __shared__ __align__(16) char Vs[2][64 * 128];
  __shared__ __align__(16) float Dn[4][32];

  // Q^T B-frags: lane holds Q[q0+w*32+q][ks*16 + hi*8 + j], ks = 0..3
  const u16* qrow = (const u16*)qh + ((size_t)bh * 2048 + q0 + w * 32 + q) * 64;
  bf16x8 qf0, qf1, qf2, qf3;
  {
    U16x8 u;
    u.u = *(const uint4*)(qrow + 0 * 16 + hi * 8); qf0 = u.v;
    u.u = *(const uint4*)(qrow + 1 * 16 + hi * 8); qf1 = u.v;
    u.u = *(const uint4*)(qrow + 2 * 16 + hi * 8); qf2 = u.v;
    u.u = *(const uint4*)(qrow + 3 * 16 + hi * 8); qf3 = u.v;
  }

  const f32x16 z16 = {0.f,0.f,0.f,0.f, 0.f,0.f,0.f,0.f, 0.f,0.f,0.f,0.f, 0.f,0.f,0.f,0.f};
  f32x16 oc0 = z16, oc1 = z16;
  float l_run = 0.f;

  const u16* kbh = (const u16*)kh + (size_t)bh * 2048 * 64;
  const u16* vbh = (const u16*)vT + (size_t)bh * 64 * 2048;

  auto stage = [&](int kvi, int buf) {
    int kbase = kvi << 6;
    #pragma unroll
    for (int cc = 0; cc < 2; ++cc) {
      int slot = w * 128 + cc * 64 + l;
      int row = slot >> 3, chs = slot & 7;
      gload_lds16(kbh + (size_t)(kbase + row) * 64 + ((chs ^ (row & 7)) << 3),
                  Ks[buf] + (w * 128 + cc * 64) * 16);
      gload_lds16(vbh + (size_t)row * 2048 + kbase + ((chs ^ (row & 7)) << 3),
                  Vs[buf] + (w * 128 + cc * 64) * 16);
    }
  };

  stage(0, 0);
  wait_vmcnt0();
  __syncthreads();

  for (int kv = 0; kv < 32; ++kv) {
    const int cur = kv & 1;
    if (kv < 31) stage(kv + 1, cur ^ 1);          // issue-early prefetch
    const char* Kc = Ks[cur];
    const char* Vc = Vs[cur];

    #pragma unroll
    for (int tt = 0; tt < 2; ++tt) {
      // ---- QK^T: S^T[k' = tt*32 + 8qd+4hi+r][q], log2 units ----
      const int arow = tt * 32 + q;
      f32x16 st = z16;
      __builtin_amdgcn_s_setprio(1);
      st = mfma32(lds_frag(Kc, arow, 0 * 32 + hi * 16, swz), qf0, st);
      st = mfma32(lds_frag(Kc, arow, 1 * 32 + hi * 16, swz), qf1, st);
      st = mfma32(lds_frag(Kc, arow, 2 * 32 + hi * 16, swz), qf2, st);
      st = mfma32(lds_frag(Kc, arow, 3 * 32 + hi * 16, swz), qf3, st);
      __builtin_amdgcn_s_setprio(0);

      // ---- softmax numerators (no max): exp2 + sum ----
      float e[16];
      #pragma unroll
      for (int i = 0; i < 16; ++i) {
        e[i] = __builtin_amdgcn_exp2f(st[i]);
        l_run += e[i];
      }

      // ---- P -> A-frags in-register: cvt_pk + permlane32_swap ----
      #pragma unroll
      for (int cc = 0; cc < 2; ++cc) {
        u32 a  = cvt_pk_bf16(e[8 * cc + 0], e[8 * cc + 1]);
        u32 b  = cvt_pk_bf16(e[8 * cc + 4], e[8 * cc + 5]);
        u32 c2 = cvt_pk_bf16(e[8 * cc + 2], e[8 * cc + 3]);
        u32 d  = cvt_pk_bf16(e[8 * cc + 6], e[8 * cc + 7]);
        permswap(a, b);
        permswap(c2, d);
        PU pu;
        pu.w[0] = a; pu.w[1] = c2; pu.w[2] = b; pu.w[3] = d;
        const int ks = tt * 2 + cc;                // global 16-k chunk
        __builtin_amdgcn_s_setprio(1);
        oc0 = mfma32(pu.v, lds_frag(Vc, q,      ks * 32 + hi * 16, swz), oc0);
        oc1 = mfma32(pu.v, lds_frag(Vc, 32 + q, ks * 32 + hi * 16, swz), oc1);
        __builtin_amdgcn_s_setprio(0);
      }
    }
    wait_vmcnt0();      // next tile's staging landed
    __syncthreads();
  }

  // ---- epilogue: denom broadcast, normalize, store ctx (B,S,E) bf16 ----
  l_run += __shfl_xor(l_run, 32);     // lanes q and q+32 hold complementary k
  Dn[w][q] = 1.f / l_run;
  __syncthreads();

  const int b = bh >> 4, hh = bh & 15;
  u16* cb = (u16*)ctx;
  #pragma unroll
  for (int qd = 0; qd < 4; ++qd) {
    float4 dv = *(const float4*)&Dn[w][qd * 8 + hi * 4];
    #pragma unroll
    for (int r = 0; r < 4; ++r) {
      float inv = (&dv.x)[r];
      int qrow_g = q0 + w * 32 + qd * 8 + hi * 4 + r;
      size_t base = ((size_t)b * 2048 + qrow_g) * 1024 + hh * 64;
      float v0 = oc0[qd * 4 + r] * inv;
      float v1 = oc1[qd * 4 + r] * inv;
      cb[base + q]      = __builtin_bit_cast(u16, (bf16_t)v0);
      cb[base + 32 + q] = __builtin_bit_cast(u16, (bf16_t)v1);
    }
  }
}

// ---------------------------------------------------------------------------
// Output projection: out[8192,64] = ctx(bf16) @ Wo + bo (fp32 out). grid = 64.
// ---------------------------------------------------------------------------
__global__ __launch_bounds__(256) void k_out_gemm(
    const bf16_t* __restrict__ ctx, const bf16_t* __restrict__ WoT,
    const float* __restrict__ bo, float* __restrict__ out) {
  int tile_m = blockIdx.x;
  const int t = threadIdx.x, l = t & 63, w = t >> 6;
  const int wm = w >> 1, wn = w & 1;
  const int c = l & 15, g = l >> 4;
  const int row0 = tile_m << 7;

  __shared__ __align__(16) char As[128 * 64 * 2];
  __shared__ __align__(16) char Bs[64 * 64 * 2];

  f32x4 acc[4][2];
  #pragma unroll
  for (int i = 0; i < 4; ++i)
    #pragma unroll
    for (int j = 0; j < 2; ++j) acc[i][j] = (f32x4){0.f, 0.f, 0.f, 0.f};

  for (int kt = 0; kt < 16; ++kt) {
    __syncthreads();
    #pragma unroll
    for (int cc = 0; cc < 4; ++cc) {
      int slot = w * 256 + cc * 64 + l;
      int row = slot >> 3, chs = slot & 7;
      const bf16_t* src = ctx + (size_t)(row0 + row) * 1024 + kt * 64 + ((chs ^ (row & 7)) << 3);
      gload_lds16(src, As + (w * 256 + cc * 64) * 16);
    }
    #pragma unroll
    for (int cc = 0; cc < 2; ++cc) {
      int slot = w * 128 + cc * 64 + l;
      int row = slot >> 3, chs = slot & 7;
      const bf16_t* src = WoT + (size_t)row * 1024 + kt * 64 + ((chs ^ (row & 7)) << 3);
      gload_lds16(src, Bs + (w * 128 + cc * 64) * 16);
    }
    wait_vmcnt0();
    __syncthreads();
    #pragma unroll
    for (int kk = 0; kk < 2; ++kk) {
      bf16x8 af[4], bfr[2];
      #pragma unroll
      for (int mi = 0; mi < 4; ++mi) {
        int row = wm * 64 + mi * 16 + c;
        U16x8 u; u.u = *(const uint4*)(As + row * 128 + ((kk * 64 + g * 16) ^ ((c & 7) << 4)));
        af[mi] = u.v;
      }
      #pragma unroll
      for (int ni = 0; ni < 2; ++ni) {
        int row = wn * 32 + ni * 16 + c;
        U16x8 u; u.u = *(const uint4*)(Bs + row * 128 + ((kk * 64 + g * 16) ^ ((c & 7) << 4)));
        bfr[ni] = u.v;
      }
      #pragma unroll
      for (int mi = 0; mi < 4; ++mi)
        #pragma unroll
        for (int ni = 0; ni < 2; ++ni)
          acc[mi][ni] = __builtin_amdgcn_mfma_f32_16x16x32_bf16(af[mi], bfr[ni], acc[mi][ni], 0, 0, 0);
    }
  }
  #pragma unroll
  for (int ni = 0; ni < 2; ++ni) {
    int col = wn * 32 + ni * 16 + c;
    float bb = bo[col];
    #pragma unroll
    for (int mi = 0; mi < 4; ++mi) {
      #pragma unroll
      for (int r = 0; r < 4; ++r) {
        int rowg = row0 + wm * 64 + mi * 16 + g * 4 + r;
        out[(size_t)rowg * 64 + col] = acc[mi][ni][r] + bb;
      }
    }
  }
}

// ---------------------------------------------------------------------------
extern "C" void kernel_launch(void* const* d_in, const int* in_sizes, int n_in,
                              void* d_out, int out_size, void* d_ws, size_t ws_size,
                              hipStream_t stream) {
  (void)in_sizes; (void)n_in; (void)out_size; (void)ws_size;
  const float* query = (const float*)d_in[0];
  const float* key_  = (const float*)d_in[1];
  const float* value = (const float*)d_in[2];
  const float* Wq = (const float*)d_in[3];
  const float* bq = (const float*)d_in[4];
  const float* Wk = (const float*)d_in[5];
  const float* bk = (const float*)d_in[6];
  const float* Wv = (const float*)d_in[7];
  const float* bv = (const float*)d_in[8];
  const float* Wo = (const float*)d_in[9];
  const float* bo = (const float*)d_in[10];
  float* out = (float*)d_out;

  char* ws = (char*)d_ws;
  bf16_t* WqT = (bf16_t*)(ws + (size_t)0);
  bf16_t* WkT = (bf16_t*)(ws + ((size_t)2 << 20));
  bf16_t* WvT = (bf16_t*)(ws + ((size_t)4 << 20));
  bf16_t* WoT = (bf16_t*)(ws + ((size_t)6 << 20));
  bf16_t* qhd = (bf16_t*)(ws + ((size_t)8 << 20));
  bf16_t* khd = (bf16_t*)(ws + ((size_t)24 << 20));
  bf16_t* vhd = (bf16_t*)(ws + ((size_t)40 << 20));
  bf16_t* vT  = (bf16_t*)(ws + ((size_t)56 << 20));
  bf16_t* ctx = (bf16_t*)(ws + ((size_t)72 << 20));

  // weight transposes (+ QSCALE folded into Wq)
  k_transpose_convert<<<256, 256, 0, stream>>>(Wq, WqT, 1024, 1024, QSCALE);
  k_transpose_convert<<<256, 256, 0, stream>>>(Wk, WkT, 1024, 1024, 1.0f);
  k_transpose_convert<<<256, 256, 0, stream>>>(Wv, WvT, 1024, 1024, 1.0f);
  k_transpose_convert<<<16, 256, 0, stream>>>(Wo, WoT, 1024, 64, 1.0f);

  k_proj_gemm<<<1536, 256, 0, stream>>>(query, key_, value, WqT, WkT, WvT,
                                        bq, bk, bv, qhd, khd, vhd);
  k_transpose_v<<<2048, 256, 0, stream>>>(vhd, vT);
  k_attn<<<1024, 256, 0, stream>>>(qhd, khd, vT, ctx);
  k_out_gemm<<<64, 256, 0, stream>>>(ctx, WoT, bo, out);
}

// Round 11
// 204.654 us; speedup vs baseline: 1.4009x; 1.2819x over previous
//
#include <hip/hip_runtime.h>
#include <hip/hip_bf16.h>
#include <cstdint>
#include <cstddef>

#define DEVI static __device__ __forceinline__

typedef unsigned short u16;
typedef unsigned int u32;
typedef __bf16 bf16_t;
typedef __bf16 bf16x8 __attribute__((ext_vector_type(8)));
typedef float f32x4 __attribute__((ext_vector_type(4)));
typedef float f32x16 __attribute__((ext_vector_type(16)));

union U16x8 { uint4 u; bf16x8 v; };
union PU { u32 w[4]; bf16x8 v; };

// 0.125 (1/sqrt(64)) * log2(e): folded into Wq/bq so scores are log2-scaled.
#define QSCALE 0.1803368801111204f

DEVI void gload_lds16(const void* g, void* l) {
  __builtin_amdgcn_global_load_lds((const __attribute__((address_space(1))) void*)g,
                                   (__attribute__((address_space(3))) void*)l, 16, 0, 0);
}
DEVI void wait_vmcnt0() { asm volatile("s_waitcnt vmcnt(0)" ::: "memory"); }

DEVI u32 pack2(float a, float b) {
  u16 x = __builtin_bit_cast(u16, (bf16_t)a);
  u16 y = __builtin_bit_cast(u16, (bf16_t)b);
  return (u32)x | ((u32)y << 16);
}

DEVI u32 cvt_pk_bf16(float lo, float hi) {
  u32 r;
  asm("v_cvt_pk_bf16_f32 %0, %1, %2" : "=v"(r) : "v"(lo), "v"(hi));
  return r;
}

// exchange: a's high-32-lane slice <-> b's low-32-lane slice
DEVI void permswap(u32& a, u32& b) {
  asm("v_permlane32_swap_b32 %0, %1" : "+v"(a), "+v"(b));
}

DEVI f32x16 mfma32(bf16x8 a, bf16x8 b, f32x16 c) {
  return __builtin_amdgcn_mfma_f32_32x32x16_bf16(a, b, c, 0, 0, 0);
}

// read one swizzled 16B fragment from a [64][128B] K/V tile
DEVI bf16x8 lds_frag(const char* base, int row, int koff, int swz) {
  U16x8 u;
  u.u = *(const uint4*)(base + row * 128 + (koff ^ swz));
  return u.v;
}

// ---------------------------------------------------------------------------
// fp32 -> bf16 convert of q/k/v activations (8192x1024 each). grid = 3*1024.
// BW-bound: 96MB read + 48MB write ~= 23us at 6.3 TB/s.
// ---------------------------------------------------------------------------
__global__ __launch_bounds__(256) void k_cvt3(
    const float* __restrict__ a, const float* __restrict__ b, const float* __restrict__ c,
    bf16_t* __restrict__ dst) {
  int which = blockIdx.x >> 10;
  int bb = blockIdx.x & 1023;
  const float* s = which == 0 ? a : which == 1 ? b : c;
  u16* d = (u16*)dst + (size_t)which * 8192 * 1024;
  size_t base = ((size_t)bb * 256 + threadIdx.x) * 8;
  #pragma unroll
  for (int p = 0; p < 4; ++p) {
    size_t i = base + (size_t)p * 2097152;
    float4 f0 = *(const float4*)(s + i);
    float4 f1 = *(const float4*)(s + i + 4);
    uint4 o;
    o.x = cvt_pk_bf16(f0.x, f0.y); o.y = cvt_pk_bf16(f0.z, f0.w);
    o.z = cvt_pk_bf16(f1.x, f1.y); o.w = cvt_pk_bf16(f1.z, f1.w);
    *(uint4*)(d + i) = o;
  }
}

// ---------------------------------------------------------------------------
// Transpose + fp32->bf16 convert (with scale): dst[C][R] = (bf16)(src[R][C]*scale)
// ---------------------------------------------------------------------------
__global__ __launch_bounds__(256) void k_transpose_convert(
    const float* __restrict__ src, bf16_t* __restrict__ dst, int R, int C, float scale) {
  int tiles_c = C >> 6;
  int tc = blockIdx.x % tiles_c;
  int tr = blockIdx.x / tiles_c;
  int r0 = tr << 6, c0 = tc << 6;
  __shared__ u16 tile[64][65];
  int t = threadIdx.x;
  #pragma unroll
  for (int p = 0; p < 4; ++p) {
    int idx = t + p * 256;
    int i = idx >> 4, j4 = (idx & 15) * 4;
    float4 f = *(const float4*)(src + (size_t)(r0 + i) * C + c0 + j4);
    tile[i][j4 + 0] = __builtin_bit_cast(u16, (bf16_t)(f.x * scale));
    tile[i][j4 + 1] = __builtin_bit_cast(u16, (bf16_t)(f.y * scale));
    tile[i][j4 + 2] = __builtin_bit_cast(u16, (bf16_t)(f.z * scale));
    tile[i][j4 + 3] = __builtin_bit_cast(u16, (bf16_t)(f.w * scale));
  }
  __syncthreads();
  #pragma unroll
  for (int p = 0; p < 2; ++p) {
    int idx = t + p * 256;
    int j = idx >> 3, i0 = (idx & 7) * 8;
    u16 us[8];
    #pragma unroll
    for (int e = 0; e < 8; ++e) us[e] = tile[i0 + e][j];
    uint4 o;
    o.x = (u32)us[0] | ((u32)us[1] << 16);
    o.y = (u32)us[2] | ((u32)us[3] << 16);
    o.z = (u32)us[4] | ((u32)us[5] << 16);
    o.w = (u32)us[6] | ((u32)us[7] << 16);
    *(uint4*)((u16*)dst + (size_t)(c0 + j) * R + r0 + i0) = o;
  }
}

// ---------------------------------------------------------------------------
// QKV projection GEMM. PRE=1: A pre-converted bf16, staged via global_load_lds
// (proven ~55us structure). PRE=0 fallback: coalesced fp32 cvt_pk staging
// (round-8, 123us, correct). BM=BN=128, BK=64, 256 thr. grid = 3*512.
// ---------------------------------------------------------------------------
template<bool PRE>
__global__ __launch_bounds__(256) void k_proj_gemm(
    const float* __restrict__ Aq, const float* __restrict__ Ak, const float* __restrict__ Av,
    const bf16_t* __restrict__ Abf,
    const bf16_t* __restrict__ WqT, const bf16_t* __restrict__ WkT, const bf16_t* __restrict__ WvT,
    const float* __restrict__ bq, const float* __restrict__ bk, const float* __restrict__ bv,
    bf16_t* __restrict__ qh, bf16_t* __restrict__ kh, bf16_t* __restrict__ vh) {
  int bx = blockIdx.x;
  int which = bx >> 9;
  int tt = bx & 511;
  int tile_m = tt & 63;
  int tile_n = tt >> 6;
  const float* A    = which == 0 ? Aq : which == 1 ? Ak : Av;
  const bf16_t* Ab  = Abf + (size_t)which * 8192 * 1024;
  const bf16_t* WT  = which == 0 ? WqT : which == 1 ? WkT : WvT;
  const float* bias = which == 0 ? bq : which == 1 ? bk : bv;
  const float bscale = which == 0 ? QSCALE : 1.0f;
  bf16_t* dst       = which == 0 ? qh : which == 1 ? kh : vh;

  const int t = threadIdx.x;
  const int l = t & 63;
  const int w = t >> 6;
  const int wm = w >> 1, wn = w & 1;
  const int c = l & 15, g = l >> 4;
  const int row0 = tile_m << 7;
  const int n0 = tile_n << 7;

  __shared__ __align__(16) char As[128 * 64 * 2];
  __shared__ __align__(16) char Bs[128 * 64 * 2];

  f32x4 acc[4][4];
  #pragma unroll
  for (int i = 0; i < 4; ++i)
    #pragma unroll
    for (int j = 0; j < 4; ++j) acc[i][j] = (f32x4){0.f, 0.f, 0.f, 0.f};

  // fallback A map: row = p*16 + (t>>4), fp32 col4 = (t&15)*4
  const int arow_b = t >> 4, ac4 = t & 15;
  const float* agbase = A + (size_t)(row0 + arow_b) * 1024 + ac4 * 4;
  char* aldst = As + arow_b * 128 + (((ac4 >> 1) ^ (arow_b & 7)) << 4) + (ac4 & 1) * 8;

  for (int kt = 0; kt < 16; ++kt) {
    __syncthreads();
    if constexpr (PRE) {
      #pragma unroll
      for (int cc = 0; cc < 4; ++cc) {
        int slot = w * 256 + cc * 64 + l;
        int row = slot >> 3, chs = slot & 7;
        const bf16_t* src = Ab + (size_t)(row0 + row) * 1024 + kt * 64 + ((chs ^ (row & 7)) << 3);
        gload_lds16(src, As + (w * 256 + cc * 64) * 16);
      }
    } else {
      const float* ap = agbase + kt * 64;
      #pragma unroll
      for (int p = 0; p < 8; ++p) {
        float4 f = *(const float4*)(ap + (size_t)p * 16384);
        uint2 o;
        o.x = cvt_pk_bf16(f.x, f.y);
        o.y = cvt_pk_bf16(f.z, f.w);
        *(uint2*)(aldst + p * 2048) = o;
      }
    }
    #pragma unroll
    for (int cc = 0; cc < 4; ++cc) {
      int slot = w * 256 + cc * 64 + l;
      int row = slot >> 3, chs = slot & 7;
      const bf16_t* src = WT + (size_t)(n0 + row) * 1024 + kt * 64 + ((chs ^ (row & 7)) << 3);
      gload_lds16(src, Bs + (w * 256 + cc * 64) * 16);
    }
    wait_vmcnt0();
    __syncthreads();
    #pragma unroll
    for (int kk = 0; kk < 2; ++kk) {
      bf16x8 af[4], bfr[4];
      #pragma unroll
      for (int mi = 0; mi < 4; ++mi) {
        int row = wm * 64 + mi * 16 + c;
        U16x8 u; u.u = *(const uint4*)(As + row * 128 + ((kk * 64 + g * 16) ^ ((c & 7) << 4)));
        af[mi] = u.v;
      }
      #pragma unroll
      for (int ni = 0; ni < 4; ++ni) {
        int row = wn * 64 + ni * 16 + c;
        U16x8 u; u.u = *(const uint4*)(Bs + row * 128 + ((kk * 64 + g * 16) ^ ((c & 7) << 4)));
        bfr[ni] = u.v;
      }
      #pragma unroll
      for (int mi = 0; mi < 4; ++mi)
        #pragma unroll
        for (int ni = 0; ni < 4; ++ni)
          acc[mi][ni] = __builtin_amdgcn_mfma_f32_16x16x32_bf16(af[mi], bfr[ni], acc[mi][ni], 0, 0, 0);
    }
  }
  u16* dd = (u16*)dst;
  #pragma unroll
  for (int ni = 0; ni < 4; ++ni) {
    int col = n0 + wn * 64 + ni * 16 + c;
    float bb = bias[col] * bscale;
    int h = col >> 6, d = col & 63;
    #pragma unroll
    for (int mi = 0; mi < 4; ++mi) {
      #pragma unroll
      for (int r = 0; r < 4; ++r) {
        int rowg = row0 + wm * 64 + mi * 16 + g * 4 + r;
        int b = rowg >> 11, s = rowg & 2047;
        float vv = acc[mi][ni][r] + bb;
        size_t idx = (((size_t)b * 16 + h) * 2048 + s) * 64 + d;
        dd[idx] = __builtin_bit_cast(u16, (bf16_t)vv);
      }
    }
  }
}

// ---------------------------------------------------------------------------
// V transpose: vh (B,H,S,Dk) -> vT (B,H,Dk,S). 64x64 tiles. grid = 64*32.
// ---------------------------------------------------------------------------
__global__ __launch_bounds__(256) void k_transpose_v(
    const bf16_t* __restrict__ vh, bf16_t* __restrict__ vT) {
  int bh = blockIdx.x >> 5, st = blockIdx.x & 31;
  int s0 = st << 6;
  __shared__ __align__(16) u16 tile[64][72];
  int t = threadIdx.x;
  const u16* src = (const u16*)vh + ((size_t)bh * 2048 + s0) * 64;
  #pragma unroll
  for (int p = 0; p < 2; ++p) {
    int idx = t + p * 256;
    int s = idx >> 3, d0 = (idx & 7) * 8;
    uint4 v = *(const uint4*)(src + s * 64 + d0);
    *(uint4*)(&tile[s][d0]) = v;
  }
  __syncthreads();
  u16* dst = (u16*)vT + (size_t)bh * 64 * 2048 + s0;
  #pragma unroll
  for (int p = 0; p < 2; ++p) {
    int idx = t + p * 256;
    int d = idx >> 3, s1 = (idx & 7) * 8;
    u16 us[8];
    #pragma unroll
    for (int e = 0; e < 8; ++e) us[e] = tile[s1 + e][d];
    uint4 o;
    o.x = (u32)us[0] | ((u32)us[1] << 16);
    o.y = (u32)us[2] | ((u32)us[3] << 16);
    o.z = (u32)us[4] | ((u32)us[5] << 16);
    o.w = (u32)us[6] | ((u32)us[7] << 16);
    *(uint4*)(dst + (size_t)d * 2048 + s1) = o;
  }
}

// ---------------------------------------------------------------------------
// Flash attention v7: 32x32x16 MFMA, P in-register via cvt_pk +
// permlane32_swap, double-buffered K/V with issue-early staging.
// grid = 1024 (XCD swizzle); 256 thr = 4 waves, wave owns 32 q rows.
// ---------------------------------------------------------------------------
__global__ __launch_bounds__(256, 4) void k_attn(
    const bf16_t* __restrict__ qh, const bf16_t* __restrict__ kh,
    const bf16_t* __restrict__ vT, bf16_t* __restrict__ ctx) {
  const int bid = blockIdx.x;
  const int bx = ((bid & 7) << 7) | (bid >> 3);   // XCD swizzle: 1024 = 8*128
  const int bh = bx >> 4;
  const int qt = bx & 15;
  const int q0 = qt << 7;                          // 128 q rows per block
  const int t = threadIdx.x, l = t & 63, w = t >> 6;  // w 0..3
  const int q = l & 31;                            // lane's q (and frag row)
  const int hi = l >> 5;                           // k-subgroup
  const int swz = (q & 7) << 4;                    // frag-read XOR

  __shared__ __align__(16) char Ks[2][64 * 128];
  __shared__ __align__(16) char Vs[2][64 * 128];
  __shared__ __align__(16) float Dn[4][32];

  // Q^T B-frags: lane holds Q[q0+w*32+q][ks*16 + hi*8 + j], ks = 0..3
  const u16* qrow = (const u16*)qh + ((size_t)bh * 2048 + q0 + w * 32 + q) * 64;
  bf16x8 qf0, qf1, qf2, qf3;
  {
    U16x8 u;
    u.u = *(const uint4*)(qrow + 0 * 16 + hi * 8); qf0 = u.v;
    u.u = *(const uint4*)(qrow + 1 * 16 + hi * 8); qf1 = u.v;
    u.u = *(const uint4*)(qrow + 2 * 16 + hi * 8); qf2 = u.v;
    u.u = *(const uint4*)(qrow + 3 * 16 + hi * 8); qf3 = u.v;
  }

  const f32x16 z16 = {0.f,0.f,0.f,0.f, 0.f,0.f,0.f,0.f, 0.f,0.f,0.f,0.f, 0.f,0.f,0.f,0.f};
  f32x16 oc0 = z16, oc1 = z16;
  float l_run = 0.f;

  const u16* kbh = (const u16*)kh + (size_t)bh * 2048 * 64;
  const u16* vbh = (const u16*)vT + (size_t)bh * 64 * 2048;

  auto stage = [&](int kvi, int buf) {
    int kbase = kvi << 6;
    #pragma unroll
    for (int cc = 0; cc < 2; ++cc) {
      int slot = w * 128 + cc * 64 + l;
      int row = slot >> 3, chs = slot & 7;
      gload_lds16(kbh + (size_t)(kbase + row) * 64 + ((chs ^ (row & 7)) << 3),
                  Ks[buf] + (w * 128 + cc * 64) * 16);
      gload_lds16(vbh + (size_t)row * 2048 + kbase + ((chs ^ (row & 7)) << 3),
                  Vs[buf] + (w * 128 + cc * 64) * 16);
    }
  };

  stage(0, 0);
  wait_vmcnt0();
  __syncthreads();

  for (int kv = 0; kv < 32; ++kv) {
    const int cur = kv & 1;
    if (kv < 31) stage(kv + 1, cur ^ 1);          // issue-early prefetch
    const char* Kc = Ks[cur];
    const char* Vc = Vs[cur];

    #pragma unroll
    for (int tt = 0; tt < 2; ++tt) {
      // ---- QK^T: S^T[k' = tt*32 + 8qd+4hi+r][q], log2 units ----
      const int arow = tt * 32 + q;
      f32x16 st = z16;
      __builtin_amdgcn_s_setprio(1);
      st = mfma32(lds_frag(Kc, arow, 0 * 32 + hi * 16, swz), qf0, st);
      st = mfma32(lds_frag(Kc, arow, 1 * 32 + hi * 16, swz), qf1, st);
      st = mfma32(lds_frag(Kc, arow, 2 * 32 + hi * 16, swz), qf2, st);
      st = mfma32(lds_frag(Kc, arow, 3 * 32 + hi * 16, swz), qf3, st);
      __builtin_amdgcn_s_setprio(0);

      // ---- softmax numerators (no max): exp2 + sum ----
      float e[16];
      #pragma unroll
      for (int i = 0; i < 16; ++i) {
        e[i] = __builtin_amdgcn_exp2f(st[i]);
        l_run += e[i];
      }

      // ---- P -> A-frags in-register: cvt_pk + permlane32_swap ----
      #pragma unroll
      for (int cc = 0; cc < 2; ++cc) {
        u32 a  = cvt_pk_bf16(e[8 * cc + 0], e[8 * cc + 1]);
        u32 b  = cvt_pk_bf16(e[8 * cc + 4], e[8 * cc + 5]);
        u32 c2 = cvt_pk_bf16(e[8 * cc + 2], e[8 * cc + 3]);
        u32 d  = cvt_pk_bf16(e[8 * cc + 6], e[8 * cc + 7]);
        permswap(a, b);
        permswap(c2, d);
        PU pu;
        pu.w[0] = a; pu.w[1] = c2; pu.w[2] = b; pu.w[3] = d;
        const int ks = tt * 2 + cc;                // global 16-k chunk
        __builtin_amdgcn_s_setprio(1);
        oc0 = mfma32(pu.v, lds_frag(Vc, q,      ks * 32 + hi * 16, swz), oc0);
        oc1 = mfma32(pu.v, lds_frag(Vc, 32 + q, ks * 32 + hi * 16, swz), oc1);
        __builtin_amdgcn_s_setprio(0);
      }
    }
    wait_vmcnt0();      // next tile's staging landed
    __syncthreads();
  }

  // ---- epilogue: denom broadcast, normalize, store ctx (B,S,E) bf16 ----
  l_run += __shfl_xor(l_run, 32);     // lanes q and q+32 hold complementary k
  Dn[w][q] = 1.f / l_run;
  __syncthreads();

  const int b = bh >> 4, hh = bh & 15;
  u16* cb = (u16*)ctx;
  #pragma unroll
  for (int qd = 0; qd < 4; ++qd) {
    float4 dv = *(const float4*)&Dn[w][qd * 8 + hi * 4];
    #pragma unroll
    for (int r = 0; r < 4; ++r) {
      float inv = (&dv.x)[r];
      int qrow_g = q0 + w * 32 + qd * 8 + hi * 4 + r;
      size_t base = ((size_t)b * 2048 + qrow_g) * 1024 + hh * 64;
      float v0 = oc0[qd * 4 + r] * inv;
      float v1 = oc1[qd * 4 + r] * inv;
      cb[base + q]      = __builtin_bit_cast(u16, (bf16_t)v0);
      cb[base + 32 + q] = __builtin_bit_cast(u16, (bf16_t)v1);
    }
  }
}

// ---------------------------------------------------------------------------
// Output projection: out[8192,64] = ctx(bf16) @ Wo + bo (fp32 out). grid = 64.
// ---------------------------------------------------------------------------
__global__ __launch_bounds__(256) void k_out_gemm(
    const bf16_t* __restrict__ ctx, const bf16_t* __restrict__ WoT,
    const float* __restrict__ bo, float* __restrict__ out) {
  int tile_m = blockIdx.x;
  const int t = threadIdx.x, l = t & 63, w = t >> 6;
  const int wm = w >> 1, wn = w & 1;
  const int c = l & 15, g = l >> 4;
  const int row0 = tile_m << 7;

  __shared__ __align__(16) char As[128 * 64 * 2];
  __shared__ __align__(16) char Bs[64 * 64 * 2];

  f32x4 acc[4][2];
  #pragma unroll
  for (int i = 0; i < 4; ++i)
    #pragma unroll
    for (int j = 0; j < 2; ++j) acc[i][j] = (f32x4){0.f, 0.f, 0.f, 0.f};

  for (int kt = 0; kt < 16; ++kt) {
    __syncthreads();
    #pragma unroll
    for (int cc = 0; cc < 4; ++cc) {
      int slot = w * 256 + cc * 64 + l;
      int row = slot >> 3, chs = slot & 7;
      const bf16_t* src = ctx + (size_t)(row0 + row) * 1024 + kt * 64 + ((chs ^ (row & 7)) << 3);
      gload_lds16(src, As + (w * 256 + cc * 64) * 16);
    }
    #pragma unroll
    for (int cc = 0; cc < 2; ++cc) {
      int slot = w * 128 + cc * 64 + l;
      int row = slot >> 3, chs = slot & 7;
      const bf16_t* src = WoT + (size_t)row * 1024 + kt * 64 + ((chs ^ (row & 7)) << 3);
      gload_lds16(src, Bs + (w * 128 + cc * 64) * 16);
    }
    wait_vmcnt0();
    __syncthreads();
    #pragma unroll
    for (int kk = 0; kk < 2; ++kk) {
      bf16x8 af[4], bfr[2];
      #pragma unroll
      for (int mi = 0; mi < 4; ++mi) {
        int row = wm * 64 + mi * 16 + c;
        U16x8 u; u.u = *(const uint4*)(As + row * 128 + ((kk * 64 + g * 16) ^ ((c & 7) << 4)));
        af[mi] = u.v;
      }
      #pragma unroll
      for (int ni = 0; ni < 2; ++ni) {
        int row = wn * 32 + ni * 16 + c;
        U16x8 u; u.u = *(const uint4*)(Bs + row * 128 + ((kk * 64 + g * 16) ^ ((c & 7) << 4)));
        bfr[ni] = u.v;
      }
      #pragma unroll
      for (int mi = 0; mi < 4; ++mi)
        #pragma unroll
        for (int ni = 0; ni < 2; ++ni)
          acc[mi][ni] = __builtin_amdgcn_mfma_f32_16x16x32_bf16(af[mi], bfr[ni], acc[mi][ni], 0, 0, 0);
    }
  }
  #pragma unroll
  for (int ni = 0; ni < 2; ++ni) {
    int col = wn * 32 + ni * 16 + c;
    float bb = bo[col];
    #pragma unroll
    for (int mi = 0; mi < 4; ++mi) {
      #pragma unroll
      for (int r = 0; r < 4; ++r) {
        int rowg = row0 + wm * 64 + mi * 16 + g * 4 + r;
        out[(size_t)rowg * 64 + col] = acc[mi][ni][r] + bb;
      }
    }
  }
}

// ---------------------------------------------------------------------------
extern "C" void kernel_launch(void* const* d_in, const int* in_sizes, int n_in,
                              void* d_out, int out_size, void* d_ws, size_t ws_size,
                              hipStream_t stream) {
  (void)in_sizes; (void)n_in; (void)out_size;
  const float* query = (const float*)d_in[0];
  const float* key_  = (const float*)d_in[1];
  const float* value = (const float*)d_in[2];
  const float* Wq = (const float*)d_in[3];
  const float* bq = (const float*)d_in[4];
  const float* Wk = (const float*)d_in[5];
  const float* bk = (const float*)d_in[6];
  const float* Wv = (const float*)d_in[7];
  const float* bv = (const float*)d_in[8];
  const float* Wo = (const float*)d_in[9];
  const float* bo = (const float*)d_in[10];
  float* out = (float*)d_out;

  char* ws = (char*)d_ws;
  bf16_t* WqT = (bf16_t*)(ws + (size_t)0);
  bf16_t* WkT = (bf16_t*)(ws + ((size_t)2 << 20));
  bf16_t* WvT = (bf16_t*)(ws + ((size_t)4 << 20));
  bf16_t* WoT = (bf16_t*)(ws + ((size_t)6 << 20));
  bf16_t* qhd = (bf16_t*)(ws + ((size_t)8 << 20));
  bf16_t* khd = (bf16_t*)(ws + ((size_t)24 << 20));
  bf16_t* vhd = (bf16_t*)(ws + ((size_t)40 << 20));
  bf16_t* vT  = (bf16_t*)(ws + ((size_t)56 << 20));
  bf16_t* ctx = (bf16_t*)(ws + ((size_t)72 << 20));
  bf16_t* Abf = (bf16_t*)(ws + ((size_t)88 << 20));   // 48 MB, proj-phase only

  const bool pre = ws_size >= ((size_t)137 << 20);

  // weight transposes (+ QSCALE folded into Wq)
  k_transpose_convert<<<256, 256, 0, stream>>>(Wq, WqT, 1024, 1024, QSCALE);
  k_transpose_convert<<<256, 256, 0, stream>>>(Wk, WkT, 1024, 1024, 1.0f);
  k_transpose_convert<<<256, 256, 0, stream>>>(Wv, WvT, 1024, 1024, 1.0f);
  k_transpose_convert<<<16, 256, 0, stream>>>(Wo, WoT, 1024, 64, 1.0f);

  if (pre) {
    k_cvt3<<<3072, 256, 0, stream>>>(query, key_, value, Abf);
    k_proj_gemm<true><<<1536, 256, 0, stream>>>(query, key_, value, Abf, WqT, WkT, WvT,
                                                bq, bk, bv, qhd, khd, vhd);
  } else {
    k_proj_gemm<false><<<1536, 256, 0, stream>>>(query, key_, value, Abf, WqT, WkT, WvT,
                                                 bq, bk, bv, qhd, khd, vhd);
  }
  k_transpose_v<<<2048, 256, 0, stream>>>(vhd, vT);
  k_attn<<<1024, 256, 0, stream>>>(qhd, khd, vT, ctx);
  k_out_gemm<<<64, 256, 0, stream>>>(ctx, WoT, bo, out);
}

// Round 12
// 194.719 us; speedup vs baseline: 1.4723x; 1.0510x over previous
//
#include <hip/hip_runtime.h>
#include <hip/hip_bf16.h>
#include <cstdint>
#include <cstddef>

#define DEVI static __device__ __forceinline__

typedef unsigned short u16;
typedef unsigned int u32;
typedef __bf16 bf16_t;
typedef __bf16 bf16x8 __attribute__((ext_vector_type(8)));
typedef float f32x4 __attribute__((ext_vector_type(4)));
typedef float f32x16 __attribute__((ext_vector_type(16)));

union U16x8 { uint4 u; bf16x8 v; };
union PU { u32 w[4]; bf16x8 v; };

// 0.125 (1/sqrt(64)) * log2(e): folded into Wq/bq so scores are log2-scaled.
#define QSCALE 0.1803368801111204f

DEVI void gload_lds16(const void* g, void* l) {
  __builtin_amdgcn_global_load_lds((const __attribute__((address_space(1))) void*)g,
                                   (__attribute__((address_space(3))) void*)l, 16, 0, 0);
}
DEVI void wait_vmcnt0() { asm volatile("s_waitcnt vmcnt(0)" ::: "memory"); }

DEVI u32 cvt_pk_bf16(float lo, float hi) {
  u32 r;
  asm("v_cvt_pk_bf16_f32 %0, %1, %2" : "=v"(r) : "v"(lo), "v"(hi));
  return r;
}

// exchange: a's high-32-lane slice <-> b's low-32-lane slice
DEVI void permswap(u32& a, u32& b) {
  asm("v_permlane32_swap_b32 %0, %1" : "+v"(a), "+v"(b));
}

DEVI f32x16 mfma32(bf16x8 a, bf16x8 b, f32x16 c) {
  return __builtin_amdgcn_mfma_f32_32x32x16_bf16(a, b, c, 0, 0, 0);
}

// read one swizzled 16B fragment from a [64][128B] K/V tile
DEVI bf16x8 lds_frag(const char* base, int row, int koff, int swz) {
  U16x8 u;
  u.u = *(const uint4*)(base + row * 128 + (koff ^ swz));
  return u.v;
}

// ---------------------------------------------------------------------------
// Merged preprocessing: blocks [0,3072): fp32->bf16 convert of q/k/v
// (8192x1024 each); blocks [3072,3840): weight transposes Wq/Wk/Wv;
// blocks [3840,3856): Wo transpose. One launch replaces five.
// ---------------------------------------------------------------------------
DEVI void transpose_body(const float* __restrict__ src, bf16_t* __restrict__ dst,
                         int R, int C, float scale, int tile, int t,
                         u16 (*tileb)[65]) {
  int tiles_c = C >> 6;
  int tc = tile % tiles_c;
  int tr = tile / tiles_c;
  int r0 = tr << 6, c0 = tc << 6;
  #pragma unroll
  for (int p = 0; p < 4; ++p) {
    int idx = t + p * 256;
    int i = idx >> 4, j4 = (idx & 15) * 4;
    float4 f = *(const float4*)(src + (size_t)(r0 + i) * C + c0 + j4);
    tileb[i][j4 + 0] = __builtin_bit_cast(u16, (bf16_t)(f.x * scale));
    tileb[i][j4 + 1] = __builtin_bit_cast(u16, (bf16_t)(f.y * scale));
    tileb[i][j4 + 2] = __builtin_bit_cast(u16, (bf16_t)(f.z * scale));
    tileb[i][j4 + 3] = __builtin_bit_cast(u16, (bf16_t)(f.w * scale));
  }
  __syncthreads();
  #pragma unroll
  for (int p = 0; p < 2; ++p) {
    int idx = t + p * 256;
    int j = idx >> 3, i0 = (idx & 7) * 8;
    u16 us[8];
    #pragma unroll
    for (int e = 0; e < 8; ++e) us[e] = tileb[i0 + e][j];
    uint4 o;
    o.x = (u32)us[0] | ((u32)us[1] << 16);
    o.y = (u32)us[2] | ((u32)us[3] << 16);
    o.z = (u32)us[4] | ((u32)us[5] << 16);
    o.w = (u32)us[6] | ((u32)us[7] << 16);
    *(uint4*)((u16*)dst + (size_t)(c0 + j) * R + r0 + i0) = o;
  }
}

__global__ __launch_bounds__(256) void k_prep(
    const float* __restrict__ qa, const float* __restrict__ ka, const float* __restrict__ va,
    const float* __restrict__ Wq, const float* __restrict__ Wk,
    const float* __restrict__ Wv, const float* __restrict__ Wo,
    bf16_t* __restrict__ Abf,
    bf16_t* __restrict__ WqT, bf16_t* __restrict__ WkT,
    bf16_t* __restrict__ WvT, bf16_t* __restrict__ WoT) {
  __shared__ u16 tileb[64][65];
  const int bid = blockIdx.x;
  const int t = threadIdx.x;
  if (bid < 3072) {
    int which = bid >> 10;
    int bb = bid & 1023;
    const float* s = which == 0 ? qa : which == 1 ? ka : va;
    u16* d = (u16*)Abf + (size_t)which * 8192 * 1024;
    size_t base = ((size_t)bb * 256 + t) * 8;
    #pragma unroll
    for (int p = 0; p < 4; ++p) {
      size_t i = base + (size_t)p * 2097152;
      float4 f0 = *(const float4*)(s + i);
      float4 f1 = *(const float4*)(s + i + 4);
      uint4 o;
      o.x = cvt_pk_bf16(f0.x, f0.y); o.y = cvt_pk_bf16(f0.z, f0.w);
      o.z = cvt_pk_bf16(f1.x, f1.y); o.w = cvt_pk_bf16(f1.z, f1.w);
      *(uint4*)(d + i) = o;
    }
  } else {
    int r = bid - 3072;
    if (r < 256)      transpose_body(Wq, WqT, 1024, 1024, QSCALE, r,       t, tileb);
    else if (r < 512) transpose_body(Wk, WkT, 1024, 1024, 1.0f,   r - 256, t, tileb);
    else if (r < 768) transpose_body(Wv, WvT, 1024, 1024, 1.0f,   r - 512, t, tileb);
    else              transpose_body(Wo, WoT, 1024, 64,   1.0f,   r - 768, t, tileb);
  }
}

// ---------------------------------------------------------------------------
// QKV projection GEMM. PRE=1: A pre-converted bf16, staged via global_load_lds
// (proven ~57us m97-class structure). PRE=0 fallback: coalesced fp32 cvt_pk
// staging. BM=BN=128, BK=64, 256 thr. grid = 3*512.
// ---------------------------------------------------------------------------
template<bool PRE>
__global__ __launch_bounds__(256) void k_proj_gemm(
    const float* __restrict__ Aq, const float* __restrict__ Ak, const float* __restrict__ Av,
    const bf16_t* __restrict__ Abf,
    const bf16_t* __restrict__ WqT, const bf16_t* __restrict__ WkT, const bf16_t* __restrict__ WvT,
    const float* __restrict__ bq, const float* __restrict__ bk, const float* __restrict__ bv,
    bf16_t* __restrict__ qh, bf16_t* __restrict__ kh, bf16_t* __restrict__ vh) {
  int bx = blockIdx.x;
  int which = bx >> 9;
  int tt = bx & 511;
  int tile_m = tt & 63;
  int tile_n = tt >> 6;
  const float* A    = which == 0 ? Aq : which == 1 ? Ak : Av;
  const bf16_t* Ab  = Abf + (size_t)which * 8192 * 1024;
  const bf16_t* WT  = which == 0 ? WqT : which == 1 ? WkT : WvT;
  const float* bias = which == 0 ? bq : which == 1 ? bk : bv;
  const float bscale = which == 0 ? QSCALE : 1.0f;
  bf16_t* dst       = which == 0 ? qh : which == 1 ? kh : vh;

  const int t = threadIdx.x;
  const int l = t & 63;
  const int w = t >> 6;
  const int wm = w >> 1, wn = w & 1;
  const int c = l & 15, g = l >> 4;
  const int row0 = tile_m << 7;
  const int n0 = tile_n << 7;

  __shared__ __align__(16) char As[128 * 64 * 2];
  __shared__ __align__(16) char Bs[128 * 64 * 2];

  f32x4 acc[4][4];
  #pragma unroll
  for (int i = 0; i < 4; ++i)
    #pragma unroll
    for (int j = 0; j < 4; ++j) acc[i][j] = (f32x4){0.f, 0.f, 0.f, 0.f};

  // fallback A map: row = p*16 + (t>>4), fp32 col4 = (t&15)*4
  const int arow_b = t >> 4, ac4 = t & 15;
  const float* agbase = A + (size_t)(row0 + arow_b) * 1024 + ac4 * 4;
  char* aldst = As + arow_b * 128 + (((ac4 >> 1) ^ (arow_b & 7)) << 4) + (ac4 & 1) * 8;

  for (int kt = 0; kt < 16; ++kt) {
    __syncthreads();
    if constexpr (PRE) {
      #pragma unroll
      for (int cc = 0; cc < 4; ++cc) {
        int slot = w * 256 + cc * 64 + l;
        int row = slot >> 3, chs = slot & 7;
        const bf16_t* src = Ab + (size_t)(row0 + row) * 1024 + kt * 64 + ((chs ^ (row & 7)) << 3);
        gload_lds16(src, As + (w * 256 + cc * 64) * 16);
      }
    } else {
      const float* ap = agbase + kt * 64;
      #pragma unroll
      for (int p = 0; p < 8; ++p) {
        float4 f = *(const float4*)(ap + (size_t)p * 16384);
        uint2 o;
        o.x = cvt_pk_bf16(f.x, f.y);
        o.y = cvt_pk_bf16(f.z, f.w);
        *(uint2*)(aldst + p * 2048) = o;
      }
    }
    #pragma unroll
    for (int cc = 0; cc < 4; ++cc) {
      int slot = w * 256 + cc * 64 + l;
      int row = slot >> 3, chs = slot & 7;
      const bf16_t* src = WT + (size_t)(n0 + row) * 1024 + kt * 64 + ((chs ^ (row & 7)) << 3);
      gload_lds16(src, Bs + (w * 256 + cc * 64) * 16);
    }
    wait_vmcnt0();
    __syncthreads();
    #pragma unroll
    for (int kk = 0; kk < 2; ++kk) {
      bf16x8 af[4], bfr[4];
      #pragma unroll
      for (int mi = 0; mi < 4; ++mi) {
        int row = wm * 64 + mi * 16 + c;
        U16x8 u; u.u = *(const uint4*)(As + row * 128 + ((kk * 64 + g * 16) ^ ((c & 7) << 4)));
        af[mi] = u.v;
      }
      #pragma unroll
      for (int ni = 0; ni < 4; ++ni) {
        int row = wn * 64 + ni * 16 + c;
        U16x8 u; u.u = *(const uint4*)(Bs + row * 128 + ((kk * 64 + g * 16) ^ ((c & 7) << 4)));
        bfr[ni] = u.v;
      }
      #pragma unroll
      for (int mi = 0; mi < 4; ++mi)
        #pragma unroll
        for (int ni = 0; ni < 4; ++ni)
          acc[mi][ni] = __builtin_amdgcn_mfma_f32_16x16x32_bf16(af[mi], bfr[ni], acc[mi][ni], 0, 0, 0);
    }
  }
  u16* dd = (u16*)dst;
  #pragma unroll
  for (int ni = 0; ni < 4; ++ni) {
    int col = n0 + wn * 64 + ni * 16 + c;
    float bb = bias[col] * bscale;
    int h = col >> 6, d = col & 63;
    #pragma unroll
    for (int mi = 0; mi < 4; ++mi) {
      #pragma unroll
      for (int r = 0; r < 4; ++r) {
        int rowg = row0 + wm * 64 + mi * 16 + g * 4 + r;
        int b = rowg >> 11, s = rowg & 2047;
        float vv = acc[mi][ni][r] + bb;
        size_t idx = (((size_t)b * 16 + h) * 2048 + s) * 64 + d;
        dd[idx] = __builtin_bit_cast(u16, (bf16_t)vv);
      }
    }
  }
}

// ---------------------------------------------------------------------------
// V transpose: vh (B,H,S,Dk) -> vT (B,H,Dk,S). 64x64 tiles. grid = 64*32.
// ---------------------------------------------------------------------------
__global__ __launch_bounds__(256) void k_transpose_v(
    const bf16_t* __restrict__ vh, bf16_t* __restrict__ vT) {
  int bh = blockIdx.x >> 5, st = blockIdx.x & 31;
  int s0 = st << 6;
  __shared__ __align__(16) u16 tile[64][72];
  int t = threadIdx.x;
  const u16* src = (const u16*)vh + ((size_t)bh * 2048 + s0) * 64;
  #pragma unroll
  for (int p = 0; p < 2; ++p) {
    int idx = t + p * 256;
    int s = idx >> 3, d0 = (idx & 7) * 8;
    uint4 v = *(const uint4*)(src + s * 64 + d0);
    *(uint4*)(&tile[s][d0]) = v;
  }
  __syncthreads();
  u16* dst = (u16*)vT + (size_t)bh * 64 * 2048 + s0;
  #pragma unroll
  for (int p = 0; p < 2; ++p) {
    int idx = t + p * 256;
    int d = idx >> 3, s1 = (idx & 7) * 8;
    u16 us[8];
    #pragma unroll
    for (int e = 0; e < 8; ++e) us[e] = tile[s1 + e][d];
    uint4 o;
    o.x = (u32)us[0] | ((u32)us[1] << 16);
    o.y = (u32)us[2] | ((u32)us[3] << 16);
    o.z = (u32)us[4] | ((u32)us[5] << 16);
    o.w = (u32)us[6] | ((u32)us[7] << 16);
    *(uint4*)(dst + (size_t)d * 2048 + s1) = o;
  }
}

// ---------------------------------------------------------------------------
// Flash attention v8: 32x32x16 MFMA, P in-register (cvt_pk + permlane32_swap),
// double-buffered K/V with issue-early staging. NEW: softmax denominator
// computed on the MFMA pipe via ones-column (sum = mfma(P, ONES, sum)) --
// removes 32 VALU adds/tile and ALL epilogue cross-lane/LDS broadcast (the
// ones-MFMA D-row mapping (reg&3)+8*(reg>>2)+4*hi matches oc0's q-row map,
// so inv = 1/sum[qd*4+r] per lane directly). grid = 1024 (XCD swizzle).
// ---------------------------------------------------------------------------
__global__ __launch_bounds__(256, 4) void k_attn(
    const bf16_t* __restrict__ qh, const bf16_t* __restrict__ kh,
    const bf16_t* __restrict__ vT, bf16_t* __restrict__ ctx) {
  const int bid = blockIdx.x;
  const int bx = ((bid & 7) << 7) | (bid >> 3);   // XCD swizzle: 1024 = 8*128
  const int bh = bx >> 4;
  const int qt = bx & 15;
  const int q0 = qt << 7;                          // 128 q rows per block
  const int t = threadIdx.x, l = t & 63, w = t >> 6;  // w 0..3
  const int q = l & 31;                            // lane's q (and frag row)
  const int hi = l >> 5;                           // k-subgroup
  const int swz = (q & 7) << 4;                    // frag-read XOR

  __shared__ __align__(16) char Ks[2][64 * 128];
  __shared__ __align__(16) char Vs[2][64 * 128];

  // Q^T B-frags: lane holds Q[q0+w*32+q][ks*16 + hi*8 + j], ks = 0..3
  const u16* qrow = (const u16*)qh + ((size_t)bh * 2048 + q0 + w * 32 + q) * 64;
  bf16x8 qf0, qf1, qf2, qf3;
  {
    U16x8 u;
    u.u = *(const uint4*)(qrow + 0 * 16 + hi * 8); qf0 = u.v;
    u.u = *(const uint4*)(qrow + 1 * 16 + hi * 8); qf1 = u.v;
    u.u = *(const uint4*)(qrow + 2 * 16 + hi * 8); qf2 = u.v;
    u.u = *(const uint4*)(qrow + 3 * 16 + hi * 8); qf3 = u.v;
  }

  bf16x8 ones;
  {
    U16x8 u;
    u.u = (uint4){0x3F803F80u, 0x3F803F80u, 0x3F803F80u, 0x3F803F80u};
    ones = u.v;
  }

  const f32x16 z16 = {0.f,0.f,0.f,0.f, 0.f,0.f,0.f,0.f, 0.f,0.f,0.f,0.f, 0.f,0.f,0.f,0.f};
  f32x16 oc0 = z16, oc1 = z16, psum = z16;

  const u16* kbh = (const u16*)kh + (size_t)bh * 2048 * 64;
  const u16* vbh = (const u16*)vT + (size_t)bh * 64 * 2048;

  auto stage = [&](int kvi, int buf) {
    int kbase = kvi << 6;
    #pragma unroll
    for (int cc = 0; cc < 2; ++cc) {
      int slot = w * 128 + cc * 64 + l;
      int row = slot >> 3, chs = slot & 7;
      gload_lds16(kbh + (size_t)(kbase + row) * 64 + ((chs ^ (row & 7)) << 3),
                  Ks[buf] + (w * 128 + cc * 64) * 16);
      gload_lds16(vbh + (size_t)row * 2048 + kbase + ((chs ^ (row & 7)) << 3),
                  Vs[buf] + (w * 128 + cc * 64) * 16);
    }
  };

  stage(0, 0);
  wait_vmcnt0();
  __syncthreads();

  for (int kv = 0; kv < 32; ++kv) {
    const int cur = kv & 1;
    if (kv < 31) stage(kv + 1, cur ^ 1);          // issue-early prefetch
    const char* Kc = Ks[cur];
    const char* Vc = Vs[cur];

    #pragma unroll
    for (int tt = 0; tt < 2; ++tt) {
      // ---- QK^T: S^T[k' = tt*32 + 8qd+4hi+r][q], log2 units ----
      const int arow = tt * 32 + q;
      f32x16 st = z16;
      __builtin_amdgcn_s_setprio(1);
      st = mfma32(lds_frag(Kc, arow, 0 * 32 + hi * 16, swz), qf0, st);
      st = mfma32(lds_frag(Kc, arow, 1 * 32 + hi * 16, swz), qf1, st);
      st = mfma32(lds_frag(Kc, arow, 2 * 32 + hi * 16, swz), qf2, st);
      st = mfma32(lds_frag(Kc, arow, 3 * 32 + hi * 16, swz), qf3, st);
      __builtin_amdgcn_s_setprio(0);

      // ---- softmax numerators (no max): exp2 ----
      float e[16];
      #pragma unroll
      for (int i = 0; i < 16; ++i) e[i] = __builtin_amdgcn_exp2f(st[i]);

      // ---- P -> A-frags in-register: cvt_pk + permlane32_swap; PV + denom ----
      #pragma unroll
      for (int cc = 0; cc < 2; ++cc) {
        u32 a  = cvt_pk_bf16(e[8 * cc + 0], e[8 * cc + 1]);
        u32 b  = cvt_pk_bf16(e[8 * cc + 4], e[8 * cc + 5]);
        u32 c2 = cvt_pk_bf16(e[8 * cc + 2], e[8 * cc + 3]);
        u32 d  = cvt_pk_bf16(e[8 * cc + 6], e[8 * cc + 7]);
        permswap(a, b);
        permswap(c2, d);
        PU pu;
        pu.w[0] = a; pu.w[1] = c2; pu.w[2] = b; pu.w[3] = d;
        const int ks = tt * 2 + cc;                // global 16-k chunk
        __builtin_amdgcn_s_setprio(1);
        oc0 = mfma32(pu.v, lds_frag(Vc, q,      ks * 32 + hi * 16, swz), oc0);
        oc1 = mfma32(pu.v, lds_frag(Vc, 32 + q, ks * 32 + hi * 16, swz), oc1);
        psum = mfma32(pu.v, ones, psum);          // denominator on MFMA pipe
        __builtin_amdgcn_s_setprio(0);
      }
    }
    wait_vmcnt0();      // next tile's staging landed
    __syncthreads();
  }

  // ---- epilogue: per-lane normalize (psum rows match oc rows), store bf16 ----
  const int b = bh >> 4, hh = bh & 15;
  u16* cb = (u16*)ctx;
  #pragma unroll
  for (int qd = 0; qd < 4; ++qd) {
    #pragma unroll
    for (int r = 0; r < 4; ++r) {
      float inv = 1.f / psum[qd * 4 + r];
      int qrow_g = q0 + w * 32 + qd * 8 + hi * 4 + r;
      size_t base = ((size_t)b * 2048 + qrow_g) * 1024 + hh * 64;
      float v0 = oc0[qd * 4 + r] * inv;
      float v1 = oc1[qd * 4 + r] * inv;
      cb[base + q]      = __builtin_bit_cast(u16, (bf16_t)v0);
      cb[base + 32 + q] = __builtin_bit_cast(u16, (bf16_t)v1);
    }
  }
}

// ---------------------------------------------------------------------------
// Output projection: out[8192,64] = ctx(bf16) @ Wo + bo (fp32 out). grid = 64.
// ---------------------------------------------------------------------------
__global__ __launch_bounds__(256) void k_out_gemm(
    const bf16_t* __restrict__ ctx, const bf16_t* __restrict__ WoT,
    const float* __restrict__ bo, float* __restrict__ out) {
  int tile_m = blockIdx.x;
  const int t = threadIdx.x, l = t & 63, w = t >> 6;
  const int wm = w >> 1, wn = w & 1;
  const int c = l & 15, g = l >> 4;
  const int row0 = tile_m << 7;

  __shared__ __align__(16) char As[128 * 64 * 2];
  __shared__ __align__(16) char Bs[64 * 64 * 2];

  f32x4 acc[4][2];
  #pragma unroll
  for (int i = 0; i < 4; ++i)
    #pragma unroll
    for (int j = 0; j < 2; ++j) acc[i][j] = (f32x4){0.f, 0.f, 0.f, 0.f};

  for (int kt = 0; kt < 16; ++kt) {
    __syncthreads();
    #pragma unroll
    for (int cc = 0; cc < 4; ++cc) {
      int slot = w * 256 + cc * 64 + l;
      int row = slot >> 3, chs = slot & 7;
      const bf16_t* src = ctx + (size_t)(row0 + row) * 1024 + kt * 64 + ((chs ^ (row & 7)) << 3);
      gload_lds16(src, As + (w * 256 + cc * 64) * 16);
    }
    #pragma unroll
    for (int cc = 0; cc < 2; ++cc) {
      int slot = w * 128 + cc * 64 + l;
      int row = slot >> 3, chs = slot & 7;
      const bf16_t* src = WoT + (size_t)row * 1024 + kt * 64 + ((chs ^ (row & 7)) << 3);
      gload_lds16(src, Bs + (w * 128 + cc * 64) * 16);
    }
    wait_vmcnt0();
    __syncthreads();
    #pragma unroll
    for (int kk = 0; kk < 2; ++kk) {
      bf16x8 af[4], bfr[2];
      #pragma unroll
      for (int mi = 0; mi < 4; ++mi) {
        int row = wm * 64 + mi * 16 + c;
        U16x8 u; u.u = *(const uint4*)(As + row * 128 + ((kk * 64 + g * 16) ^ ((c & 7) << 4)));
        af[mi] = u.v;
      }
      #pragma unroll
      for (int ni = 0; ni < 2; ++ni) {
        int row = wn * 32 + ni * 16 + c;
        U16x8 u; u.u = *(const uint4*)(Bs + row * 128 + ((kk * 64 + g * 16) ^ ((c & 7) << 4)));
        bfr[ni] = u.v;
      }
      #pragma unroll
      for (int mi = 0; mi < 4; ++mi)
        #pragma unroll
        for (int ni = 0; ni < 2; ++ni)
          acc[mi][ni] = __builtin_amdgcn_mfma_f32_16x16x32_bf16(af[mi], bfr[ni], acc[mi][ni], 0, 0, 0);
    }
  }
  #pragma unroll
  for (int ni = 0; ni < 2; ++ni) {
    int col = wn * 32 + ni * 16 + c;
    float bb = bo[col];
    #pragma unroll
    for (int mi = 0; mi < 4; ++mi) {
      #pragma unroll
      for (int r = 0; r < 4; ++r) {
        int rowg = row0 + wm * 64 + mi * 16 + g * 4 + r;
        out[(size_t)rowg * 64 + col] = acc[mi][ni][r] + bb;
      }
    }
  }
}

// ---------------------------------------------------------------------------
extern "C" void kernel_launch(void* const* d_in, const int* in_sizes, int n_in,
                              void* d_out, int out_size, void* d_ws, size_t ws_size,
                              hipStream_t stream) {
  (void)in_sizes; (void)n_in; (void)out_size;
  const float* query = (const float*)d_in[0];
  const float* key_  = (const float*)d_in[1];
  const float* value = (const float*)d_in[2];
  const float* Wq = (const float*)d_in[3];
  const float* bq = (const float*)d_in[4];
  const float* Wk = (const float*)d_in[5];
  const float* bk = (const float*)d_in[6];
  const float* Wv = (const float*)d_in[7];
  const float* bv = (const float*)d_in[8];
  const float* Wo = (const float*)d_in[9];
  const float* bo = (const float*)d_in[10];
  float* out = (float*)d_out;

  char* ws = (char*)d_ws;
  bf16_t* WqT = (bf16_t*)(ws + (size_t)0);
  bf16_t* WkT = (bf16_t*)(ws + ((size_t)2 << 20));
  bf16_t* WvT = (bf16_t*)(ws + ((size_t)4 << 20));
  bf16_t* WoT = (bf16_t*)(ws + ((size_t)6 << 20));
  bf16_t* qhd = (bf16_t*)(ws + ((size_t)8 << 20));
  bf16_t* khd = (bf16_t*)(ws + ((size_t)24 << 20));
  bf16_t* vhd = (bf16_t*)(ws + ((size_t)40 << 20));
  bf16_t* vT  = (bf16_t*)(ws + ((size_t)56 << 20));
  bf16_t* ctx = (bf16_t*)(ws + ((size_t)72 << 20));
  bf16_t* Abf = (bf16_t*)(ws + ((size_t)88 << 20));   // 48 MB, proj-phase only

  const bool pre = ws_size >= ((size_t)137 << 20);

  if (pre) {
    k_prep<<<3856, 256, 0, stream>>>(query, key_, value, Wq, Wk, Wv, Wo,
                                     Abf, WqT, WkT, WvT, WoT);
    k_proj_gemm<true><<<1536, 256, 0, stream>>>(query, key_, value, Abf, WqT, WkT, WvT,
                                                bq, bk, bv, qhd, khd, vhd);
  } else {
    k_prep<<<3856, 256, 0, stream>>>(query, key_, value, Wq, Wk, Wv, Wo,
                                     Abf, WqT, WkT, WvT, WoT);   // Abf unused by PRE=0
    k_proj_gemm<false><<<1536, 256, 0, stream>>>(query, key_, value, Abf, WqT, WkT, WvT,
                                                 bq, bk, bv, qhd, khd, vhd);
  }
  k_transpose_v<<<2048, 256, 0, stream>>>(vhd, vT);
  k_attn<<<1024, 256, 0, stream>>>(qhd, khd, vT, ctx);
  k_out_gemm<<<64, 256, 0, stream>>>(ctx, WoT, bo, out);
}

// Round 13
// 186.384 us; speedup vs baseline: 1.5382x; 1.0447x over previous
//
#include <hip/hip_runtime.h>
#include <hip/hip_bf16.h>
#include <cstdint>
#include <cstddef>

#define DEVI static __device__ __forceinline__

typedef unsigned short u16;
typedef unsigned int u32;
typedef __bf16 bf16_t;
typedef __bf16 bf16x8 __attribute__((ext_vector_type(8)));
typedef float f32x4 __attribute__((ext_vector_type(4)));
typedef float f32x16 __attribute__((ext_vector_type(16)));

union U16x8 { uint4 u; bf16x8 v; };
union PU { u32 w[4]; bf16x8 v; };

// 0.125 (1/sqrt(64)) * log2(e): folded into Wq/bq so scores are log2-scaled.
#define QSCALE 0.1803368801111204f

DEVI void gload_lds16(const void* g, void* l) {
  __builtin_amdgcn_global_load_lds((const __attribute__((address_space(1))) void*)g,
                                   (__attribute__((address_space(3))) void*)l, 16, 0, 0);
}
DEVI void wait_vmcnt0() { asm volatile("s_waitcnt vmcnt(0)" ::: "memory"); }

DEVI u32 cvt_pk_bf16(float lo, float hi) {
  u32 r;
  asm("v_cvt_pk_bf16_f32 %0, %1, %2" : "=v"(r) : "v"(lo), "v"(hi));
  return r;
}

// exchange: a's high-32-lane slice <-> b's low-32-lane slice
DEVI void permswap(u32& a, u32& b) {
  asm("v_permlane32_swap_b32 %0, %1" : "+v"(a), "+v"(b));
}

DEVI f32x16 mfma32(bf16x8 a, bf16x8 b, f32x16 c) {
  return __builtin_amdgcn_mfma_f32_32x32x16_bf16(a, b, c, 0, 0, 0);
}

// read one swizzled 16B fragment from a [64][128B] K/V tile
DEVI bf16x8 lds_frag(const char* base, int row, int koff, int swz) {
  U16x8 u;
  u.u = *(const uint4*)(base + row * 128 + (koff ^ swz));
  return u.v;
}

// ---------------------------------------------------------------------------
// Merged preprocessing: blocks [0,3072): fp32->bf16 convert of q/k/v;
// blocks [3072,3840): weight transposes Wq/Wk/Wv; [3840,3856): Wo.
// ---------------------------------------------------------------------------
DEVI void transpose_body(const float* __restrict__ src, bf16_t* __restrict__ dst,
                         int R, int C, float scale, int tile, int t,
                         u16 (*tileb)[65]) {
  int tiles_c = C >> 6;
  int tc = tile % tiles_c;
  int tr = tile / tiles_c;
  int r0 = tr << 6, c0 = tc << 6;
  #pragma unroll
  for (int p = 0; p < 4; ++p) {
    int idx = t + p * 256;
    int i = idx >> 4, j4 = (idx & 15) * 4;
    float4 f = *(const float4*)(src + (size_t)(r0 + i) * C + c0 + j4);
    tileb[i][j4 + 0] = __builtin_bit_cast(u16, (bf16_t)(f.x * scale));
    tileb[i][j4 + 1] = __builtin_bit_cast(u16, (bf16_t)(f.y * scale));
    tileb[i][j4 + 2] = __builtin_bit_cast(u16, (bf16_t)(f.z * scale));
    tileb[i][j4 + 3] = __builtin_bit_cast(u16, (bf16_t)(f.w * scale));
  }
  __syncthreads();
  #pragma unroll
  for (int p = 0; p < 2; ++p) {
    int idx = t + p * 256;
    int j = idx >> 3, i0 = (idx & 7) * 8;
    u16 us[8];
    #pragma unroll
    for (int e = 0; e < 8; ++e) us[e] = tileb[i0 + e][j];
    uint4 o;
    o.x = (u32)us[0] | ((u32)us[1] << 16);
    o.y = (u32)us[2] | ((u32)us[3] << 16);
    o.z = (u32)us[4] | ((u32)us[5] << 16);
    o.w = (u32)us[6] | ((u32)us[7] << 16);
    *(uint4*)((u16*)dst + (size_t)(c0 + j) * R + r0 + i0) = o;
  }
}

__global__ __launch_bounds__(256) void k_prep(
    const float* __restrict__ qa, const float* __restrict__ ka, const float* __restrict__ va,
    const float* __restrict__ Wq, const float* __restrict__ Wk,
    const float* __restrict__ Wv, const float* __restrict__ Wo,
    bf16_t* __restrict__ Abf,
    bf16_t* __restrict__ WqT, bf16_t* __restrict__ WkT,
    bf16_t* __restrict__ WvT, bf16_t* __restrict__ WoT) {
  __shared__ u16 tileb[64][65];
  const int bid = blockIdx.x;
  const int t = threadIdx.x;
  if (bid < 3072) {
    int which = bid >> 10;
    int bb = bid & 1023;
    const float* s = which == 0 ? qa : which == 1 ? ka : va;
    u16* d = (u16*)Abf + (size_t)which * 8192 * 1024;
    size_t base = ((size_t)bb * 256 + t) * 8;
    #pragma unroll
    for (int p = 0; p < 4; ++p) {
      size_t i = base + (size_t)p * 2097152;
      float4 f0 = *(const float4*)(s + i);
      float4 f1 = *(const float4*)(s + i + 4);
      uint4 o;
      o.x = cvt_pk_bf16(f0.x, f0.y); o.y = cvt_pk_bf16(f0.z, f0.w);
      o.z = cvt_pk_bf16(f1.x, f1.y); o.w = cvt_pk_bf16(f1.z, f1.w);
      *(uint4*)(d + i) = o;
    }
  } else {
    int r = bid - 3072;
    if (r < 256)      transpose_body(Wq, WqT, 1024, 1024, QSCALE, r,       t, tileb);
    else if (r < 512) transpose_body(Wk, WkT, 1024, 1024, 1.0f,   r - 256, t, tileb);
    else if (r < 768) transpose_body(Wv, WvT, 1024, 1024, 1.0f,   r - 512, t, tileb);
    else              transpose_body(Wo, WoT, 1024, 64,   1.0f,   r - 768, t, tileb);
  }
}

// ---------------------------------------------------------------------------
// QKV projection GEMM. PRE=1: A pre-converted bf16, staged via global_load_lds.
// which==0/1 (q,k): epilogue scatters to (B,H,S,Dk). which==2 (v): epilogue
// writes vT (B,H,Dk,S) DIRECTLY (packed 8B stores of 4 consecutive-s values)
// -- replaces the separate k_transpose_v kernel. BM=BN=128, BK=64. grid=3*512.
// ---------------------------------------------------------------------------
template<bool PRE>
__global__ __launch_bounds__(256) void k_proj_gemm(
    const float* __restrict__ Aq, const float* __restrict__ Ak, const float* __restrict__ Av,
    const bf16_t* __restrict__ Abf,
    const bf16_t* __restrict__ WqT, const bf16_t* __restrict__ WkT, const bf16_t* __restrict__ WvT,
    const float* __restrict__ bq, const float* __restrict__ bk, const float* __restrict__ bv,
    bf16_t* __restrict__ qh, bf16_t* __restrict__ kh, bf16_t* __restrict__ vT) {
  int bx = blockIdx.x;
  int which = bx >> 9;
  int tt = bx & 511;
  int tile_m = tt & 63;
  int tile_n = tt >> 6;
  const float* A    = which == 0 ? Aq : which == 1 ? Ak : Av;
  const bf16_t* Ab  = Abf + (size_t)which * 8192 * 1024;
  const bf16_t* WT  = which == 0 ? WqT : which == 1 ? WkT : WvT;
  const float* bias = which == 0 ? bq : which == 1 ? bk : bv;
  const float bscale = which == 0 ? QSCALE : 1.0f;

  const int t = threadIdx.x;
  const int l = t & 63;
  const int w = t >> 6;
  const int wm = w >> 1, wn = w & 1;
  const int c = l & 15, g = l >> 4;
  const int row0 = tile_m << 7;
  const int n0 = tile_n << 7;

  __shared__ __align__(16) char As[128 * 64 * 2];
  __shared__ __align__(16) char Bs[128 * 64 * 2];

  f32x4 acc[4][4];
  #pragma unroll
  for (int i = 0; i < 4; ++i)
    #pragma unroll
    for (int j = 0; j < 4; ++j) acc[i][j] = (f32x4){0.f, 0.f, 0.f, 0.f};

  // fallback A map: row = p*16 + (t>>4), fp32 col4 = (t&15)*4
  const int arow_b = t >> 4, ac4 = t & 15;
  const float* agbase = A + (size_t)(row0 + arow_b) * 1024 + ac4 * 4;
  char* aldst = As + arow_b * 128 + (((ac4 >> 1) ^ (arow_b & 7)) << 4) + (ac4 & 1) * 8;

  for (int kt = 0; kt < 16; ++kt) {
    __syncthreads();
    if constexpr (PRE) {
      #pragma unroll
      for (int cc = 0; cc < 4; ++cc) {
        int slot = w * 256 + cc * 64 + l;
        int row = slot >> 3, chs = slot & 7;
        const bf16_t* src = Ab + (size_t)(row0 + row) * 1024 + kt * 64 + ((chs ^ (row & 7)) << 3);
        gload_lds16(src, As + (w * 256 + cc * 64) * 16);
      }
    } else {
      const float* ap = agbase + kt * 64;
      #pragma unroll
      for (int p = 0; p < 8; ++p) {
        float4 f = *(const float4*)(ap + (size_t)p * 16384);
        uint2 o;
        o.x = cvt_pk_bf16(f.x, f.y);
        o.y = cvt_pk_bf16(f.z, f.w);
        *(uint2*)(aldst + p * 2048) = o;
      }
    }
    #pragma unroll
    for (int cc = 0; cc < 4; ++cc) {
      int slot = w * 256 + cc * 64 + l;
      int row = slot >> 3, chs = slot & 7;
      const bf16_t* src = WT + (size_t)(n0 + row) * 1024 + kt * 64 + ((chs ^ (row & 7)) << 3);
      gload_lds16(src, Bs + (w * 256 + cc * 64) * 16);
    }
    wait_vmcnt0();
    __syncthreads();
    #pragma unroll
    for (int kk = 0; kk < 2; ++kk) {
      bf16x8 af[4], bfr[4];
      #pragma unroll
      for (int mi = 0; mi < 4; ++mi) {
        int row = wm * 64 + mi * 16 + c;
        U16x8 u; u.u = *(const uint4*)(As + row * 128 + ((kk * 64 + g * 16) ^ ((c & 7) << 4)));
        af[mi] = u.v;
      }
      #pragma unroll
      for (int ni = 0; ni < 4; ++ni) {
        int row = wn * 64 + ni * 16 + c;
        U16x8 u; u.u = *(const uint4*)(Bs + row * 128 + ((kk * 64 + g * 16) ^ ((c & 7) << 4)));
        bfr[ni] = u.v;
      }
      #pragma unroll
      for (int mi = 0; mi < 4; ++mi)
        #pragma unroll
        for (int ni = 0; ni < 4; ++ni)
          acc[mi][ni] = __builtin_amdgcn_mfma_f32_16x16x32_bf16(af[mi], bfr[ni], acc[mi][ni], 0, 0, 0);
    }
  }

  const int b = row0 >> 11;            // batch: constant per block (128 | 2048)
  const int sl0 = row0 & 2047;         // s offset of block within batch
  if (which == 2) {
    // ---- V epilogue: write vT[(b*16+h)*64+d][s] directly ----
    u16* vbase = (u16*)vT;
    #pragma unroll
    for (int ni = 0; ni < 4; ++ni) {
      int col = n0 + wn * 64 + ni * 16 + c;
      float bb = bias[col];
      int h = col >> 6, d = col & 63;
      u16* rowp = vbase + (((size_t)(b * 16 + h) * 64 + d) * 2048);
      #pragma unroll
      for (int mi = 0; mi < 4; ++mi) {
        int s = sl0 + wm * 64 + mi * 16 + g * 4;   // 4 consecutive s
        uint2 pv;
        pv.x = cvt_pk_bf16(acc[mi][ni][0] + bb, acc[mi][ni][1] + bb);
        pv.y = cvt_pk_bf16(acc[mi][ni][2] + bb, acc[mi][ni][3] + bb);
        *(uint2*)(rowp + s) = pv;
      }
    }
  } else {
    bf16_t* dst = which == 0 ? qh : kh;
    u16* dd = (u16*)dst;
    #pragma unroll
    for (int ni = 0; ni < 4; ++ni) {
      int col = n0 + wn * 64 + ni * 16 + c;
      float bb = bias[col] * bscale;
      int h = col >> 6, d = col & 63;
      #pragma unroll
      for (int mi = 0; mi < 4; ++mi) {
        #pragma unroll
        for (int r = 0; r < 4; ++r) {
          int s = sl0 + wm * 64 + mi * 16 + g * 4 + r;
          float vv = acc[mi][ni][r] + bb;
          size_t idx = (((size_t)b * 16 + h) * 2048 + s) * 64 + d;
          dd[idx] = __builtin_bit_cast(u16, (bf16_t)vv);
        }
      }
    }
  }
}

// ---------------------------------------------------------------------------
// Flash attention v8: 32x32x16 MFMA, P in-register (cvt_pk + permlane32_swap),
// double-buffered K/V with issue-early staging; denominator on the MFMA pipe
// via ones-column. grid = 1024 (XCD swizzle); 4 waves, wave owns 32 q rows.
// ---------------------------------------------------------------------------
__global__ __launch_bounds__(256, 4) void k_attn(
    const bf16_t* __restrict__ qh, const bf16_t* __restrict__ kh,
    const bf16_t* __restrict__ vT, bf16_t* __restrict__ ctx) {
  const int bid = blockIdx.x;
  const int bx = ((bid & 7) << 7) | (bid >> 3);   // XCD swizzle: 1024 = 8*128
  const int bh = bx >> 4;
  const int qt = bx & 15;
  const int q0 = qt << 7;                          // 128 q rows per block
  const int t = threadIdx.x, l = t & 63, w = t >> 6;  // w 0..3
  const int q = l & 31;                            // lane's q (and frag row)
  const int hi = l >> 5;                           // k-subgroup
  const int swz = (q & 7) << 4;                    // frag-read XOR

  __shared__ __align__(16) char Ks[2][64 * 128];
  __shared__ __align__(16) char Vs[2][64 * 128];

  // Q^T B-frags: lane holds Q[q0+w*32+q][ks*16 + hi*8 + j], ks = 0..3
  const u16* qrow = (const u16*)qh + ((size_t)bh * 2048 + q0 + w * 32 + q) * 64;
  bf16x8 qf0, qf1, qf2, qf3;
  {
    U16x8 u;
    u.u = *(const uint4*)(qrow + 0 * 16 + hi * 8); qf0 = u.v;
    u.u = *(const uint4*)(qrow + 1 * 16 + hi * 8); qf1 = u.v;
    u.u = *(const uint4*)(qrow + 2 * 16 + hi * 8); qf2 = u.v;
    u.u = *(const uint4*)(qrow + 3 * 16 + hi * 8); qf3 = u.v;
  }

  bf16x8 ones;
  {
    U16x8 u;
    u.u = (uint4){0x3F803F80u, 0x3F803F80u, 0x3F803F80u, 0x3F803F80u};
    ones = u.v;
  }

  const f32x16 z16 = {0.f,0.f,0.f,0.f, 0.f,0.f,0.f,0.f, 0.f,0.f,0.f,0.f, 0.f,0.f,0.f,0.f};
  f32x16 oc0 = z16, oc1 = z16, psum = z16;

  const u16* kbh = (const u16*)kh + (size_t)bh * 2048 * 64;
  const u16* vbh = (const u16*)vT + (size_t)bh * 64 * 2048;

  auto stage = [&](int kvi, int buf) {
    int kbase = kvi << 6;
    #pragma unroll
    for (int cc = 0; cc < 2; ++cc) {
      int slot = w * 128 + cc * 64 + l;
      int row = slot >> 3, chs = slot & 7;
      gload_lds16(kbh + (size_t)(kbase + row) * 64 + ((chs ^ (row & 7)) << 3),
                  Ks[buf] + (w * 128 + cc * 64) * 16);
      gload_lds16(vbh + (size_t)row * 2048 + kbase + ((chs ^ (row & 7)) << 3),
                  Vs[buf] + (w * 128 + cc * 64) * 16);
    }
  };

  stage(0, 0);
  wait_vmcnt0();
  __syncthreads();

  for (int kv = 0; kv < 32; ++kv) {
    const int cur = kv & 1;
    if (kv < 31) stage(kv + 1, cur ^ 1);          // issue-early prefetch
    const char* Kc = Ks[cur];
    const char* Vc = Vs[cur];

    #pragma unroll
    for (int tt = 0; tt < 2; ++tt) {
      // ---- QK^T: S^T[k' = tt*32 + 8qd+4hi+r][q], log2 units ----
      const int arow = tt * 32 + q;
      f32x16 st = z16;
      __builtin_amdgcn_s_setprio(1);
      st = mfma32(lds_frag(Kc, arow, 0 * 32 + hi * 16, swz), qf0, st);
      st = mfma32(lds_frag(Kc, arow, 1 * 32 + hi * 16, swz), qf1, st);
      st = mfma32(lds_frag(Kc, arow, 2 * 32 + hi * 16, swz), qf2, st);
      st = mfma32(lds_frag(Kc, arow, 3 * 32 + hi * 16, swz), qf3, st);
      __builtin_amdgcn_s_setprio(0);

      // ---- softmax numerators (no max): exp2 ----
      float e[16];
      #pragma unroll
      for (int i = 0; i < 16; ++i) e[i] = __builtin_amdgcn_exp2f(st[i]);

      // ---- P -> A-frags in-register: cvt_pk + permlane32_swap; PV + denom ----
      #pragma unroll
      for (int cc = 0; cc < 2; ++cc) {
        u32 a  = cvt_pk_bf16(e[8 * cc + 0], e[8 * cc + 1]);
        u32 b  = cvt_pk_bf16(e[8 * cc + 4], e[8 * cc + 5]);
        u32 c2 = cvt_pk_bf16(e[8 * cc + 2], e[8 * cc + 3]);
        u32 d  = cvt_pk_bf16(e[8 * cc + 6], e[8 * cc + 7]);
        permswap(a, b);
        permswap(c2, d);
        PU pu;
        pu.w[0] = a; pu.w[1] = c2; pu.w[2] = b; pu.w[3] = d;
        const int ks = tt * 2 + cc;                // global 16-k chunk
        __builtin_amdgcn_s_setprio(1);
        oc0 = mfma32(pu.v, lds_frag(Vc, q,      ks * 32 + hi * 16, swz), oc0);
        oc1 = mfma32(pu.v, lds_frag(Vc, 32 + q, ks * 32 + hi * 16, swz), oc1);
        psum = mfma32(pu.v, ones, psum);          // denominator on MFMA pipe
        __builtin_amdgcn_s_setprio(0);
      }
    }
    wait_vmcnt0();      // next tile's staging landed
    __syncthreads();
  }

  // ---- epilogue: per-lane normalize (psum rows match oc rows), store bf16 ----
  const int b = bh >> 4, hh = bh & 15;
  u16* cb = (u16*)ctx;
  #pragma unroll
  for (int qd = 0; qd < 4; ++qd) {
    #pragma unroll
    for (int r = 0; r < 4; ++r) {
      float inv = 1.f / psum[qd * 4 + r];
      int qrow_g = q0 + w * 32 + qd * 8 + hi * 4 + r;
      size_t base = ((size_t)b * 2048 + qrow_g) * 1024 + hh * 64;
      float v0 = oc0[qd * 4 + r] * inv;
      float v1 = oc1[qd * 4 + r] * inv;
      cb[base + q]      = __builtin_bit_cast(u16, (bf16_t)v0);
      cb[base + 32 + q] = __builtin_bit_cast(u16, (bf16_t)v1);
    }
  }
}

// ---------------------------------------------------------------------------
// Output projection: out[8192,64] = ctx(bf16) @ Wo + bo (fp32 out).
// BM=32, BN=64, BK=64 -> grid = 256 (full CU coverage; BW-bound).
// 4 waves as 2x2: wave = 16 rows x 32 cols.
// ---------------------------------------------------------------------------
__global__ __launch_bounds__(256) void k_out_gemm(
    const bf16_t* __restrict__ ctx, const bf16_t* __restrict__ WoT,
    const float* __restrict__ bo, float* __restrict__ out) {
  int tile_m = blockIdx.x;
  const int t = threadIdx.x, l = t & 63, w = t >> 6;
  const int wm = w >> 1, wn = w & 1;
  const int c = l & 15, g = l >> 4;
  const int row0 = tile_m << 5;

  __shared__ __align__(16) char As[32 * 64 * 2];
  __shared__ __align__(16) char Bs[64 * 64 * 2];

  f32x4 acc[2];
  acc[0] = (f32x4){0.f, 0.f, 0.f, 0.f};
  acc[1] = (f32x4){0.f, 0.f, 0.f, 0.f};

  for (int kt = 0; kt < 16; ++kt) {
    __syncthreads();
    {
      int row = t >> 3, chs = t & 7;       // 256 slots cover 32x64 A
      const bf16_t* src = ctx + (size_t)(row0 + row) * 1024 + kt * 64 + ((chs ^ (row & 7)) << 3);
      gload_lds16(src, As + t * 16);
    }
    #pragma unroll
    for (int cc = 0; cc < 2; ++cc) {
      int slot = w * 128 + cc * 64 + l;
      int row = slot >> 3, chs = slot & 7;
      const bf16_t* src = WoT + (size_t)row * 1024 + kt * 64 + ((chs ^ (row & 7)) << 3);
      gload_lds16(src, Bs + (w * 128 + cc * 64) * 16);
    }
    wait_vmcnt0();
    __syncthreads();
    #pragma unroll
    for (int kk = 0; kk < 2; ++kk) {
      bf16x8 af;
      {
        int row = wm * 16 + c;
        U16x8 u; u.u = *(const uint4*)(As + row * 128 + ((kk * 64 + g * 16) ^ ((c & 7) << 4)));
        af = u.v;
      }
      #pragma unroll
      for (int ni = 0; ni < 2; ++ni) {
        int row = wn * 32 + ni * 16 + c;
        U16x8 u; u.u = *(const uint4*)(Bs + row * 128 + ((kk * 64 + g * 16) ^ ((c & 7) << 4)));
        acc[ni] = __builtin_amdgcn_mfma_f32_16x16x32_bf16(af, u.v, acc[ni], 0, 0, 0);
      }
    }
  }
  #pragma unroll
  for (int ni = 0; ni < 2; ++ni) {
    int col = wn * 32 + ni * 16 + c;
    float bb = bo[col];
    #pragma unroll
    for (int r = 0; r < 4; ++r) {
      int rowg = row0 + wm * 16 + g * 4 + r;
      out[(size_t)rowg * 64 + col] = acc[ni][r] + bb;
    }
  }
}

// ---------------------------------------------------------------------------
extern "C" void kernel_launch(void* const* d_in, const int* in_sizes, int n_in,
                              void* d_out, int out_size, void* d_ws, size_t ws_size,
                              hipStream_t stream) {
  (void)in_sizes; (void)n_in; (void)out_size;
  const float* query = (const float*)d_in[0];
  const float* key_  = (const float*)d_in[1];
  const float* value = (const float*)d_in[2];
  const float* Wq = (const float*)d_in[3];
  const float* bq = (const float*)d_in[4];
  const float* Wk = (const float*)d_in[5];
  const float* bk = (const float*)d_in[6];
  const float* Wv = (const float*)d_in[7];
  const float* bv = (const float*)d_in[8];
  const float* Wo = (const float*)d_in[9];
  const float* bo = (const float*)d_in[10];
  float* out = (float*)d_out;

  char* ws = (char*)d_ws;
  bf16_t* WqT = (bf16_t*)(ws + (size_t)0);
  bf16_t* WkT = (bf16_t*)(ws + ((size_t)2 << 20));
  bf16_t* WvT = (bf16_t*)(ws + ((size_t)4 << 20));
  bf16_t* WoT = (bf16_t*)(ws + ((size_t)6 << 20));
  bf16_t* qhd = (bf16_t*)(ws + ((size_t)8 << 20));
  bf16_t* khd = (bf16_t*)(ws + ((size_t)24 << 20));
  bf16_t* vT  = (bf16_t*)(ws + ((size_t)56 << 20));
  bf16_t* ctx = (bf16_t*)(ws + ((size_t)72 << 20));
  bf16_t* Abf = (bf16_t*)(ws + ((size_t)88 << 20));   // 48 MB, proj-phase only

  const bool pre = ws_size >= ((size_t)137 << 20);

  k_prep<<<3856, 256, 0, stream>>>(query, key_, value, Wq, Wk, Wv, Wo,
                                   Abf, WqT, WkT, WvT, WoT);
  if (pre) {
    k_proj_gemm<true><<<1536, 256, 0, stream>>>(query, key_, value, Abf, WqT, WkT, WvT,
                                                bq, bk, bv, qhd, khd, vT);
  } else {
    k_proj_gemm<false><<<1536, 256, 0, stream>>>(query, key_, value, Abf, WqT, WkT, WvT,
                                                 bq, bk, bv, qhd, khd, vT);
  }
  k_attn<<<1024, 256, 0, stream>>>(qhd, khd, vT, ctx);
  k_out_gemm<<<256, 256, 0, stream>>>(ctx, WoT, bo, out);
}

// Round 14
// 180.386 us; speedup vs baseline: 1.5893x; 1.0332x over previous
//
#include <hip/hip_runtime.h>
#include <hip/hip_bf16.h>
#include <cstdint>
#include <cstddef>

#define DEVI static __device__ __forceinline__

typedef unsigned short u16;
typedef unsigned int u32;
typedef __bf16 bf16_t;
typedef __bf16 bf16x8 __attribute__((ext_vector_type(8)));
typedef float f32x4 __attribute__((ext_vector_type(4)));
typedef float f32x16 __attribute__((ext_vector_type(16)));

union U16x8 { uint4 u; bf16x8 v; };
union PU { u32 w[4]; bf16x8 v; };

// 0.125 (1/sqrt(64)) * log2(e): folded into Wq/bq so scores are log2-scaled.
#define QSCALE 0.1803368801111204f

DEVI void gload_lds16(const void* g, void* l) {
  __builtin_amdgcn_global_load_lds((const __attribute__((address_space(1))) void*)g,
                                   (__attribute__((address_space(3))) void*)l, 16, 0, 0);
}
DEVI void wait_vmcnt0() { asm volatile("s_waitcnt vmcnt(0)" ::: "memory"); }

DEVI u32 cvt_pk_bf16(float lo, float hi) {
  u32 r;
  asm("v_cvt_pk_bf16_f32 %0, %1, %2" : "=v"(r) : "v"(lo), "v"(hi));
  return r;
}

// exchange: a's high-32-lane slice <-> b's low-32-lane slice
DEVI void permswap(u32& a, u32& b) {
  asm("v_permlane32_swap_b32 %0, %1" : "+v"(a), "+v"(b));
}

DEVI f32x16 mfma32(bf16x8 a, bf16x8 b, f32x16 c) {
  return __builtin_amdgcn_mfma_f32_32x32x16_bf16(a, b, c, 0, 0, 0);
}

// read one swizzled 16B fragment; row stride templated (128B K rows, 256B V rows)
template<int STRIDE>
DEVI bf16x8 lds_frag(const char* base, int row, int koff, int swz) {
  U16x8 u;
  u.u = *(const uint4*)(base + row * STRIDE + (koff ^ swz));
  return u.v;
}

// ---------------------------------------------------------------------------
// Merged preprocessing: blocks [0,3072): fp32->bf16 convert of q/k/v;
// blocks [3072,3840): weight transposes Wq/Wk/Wv; [3840,3856): Wo.
// ---------------------------------------------------------------------------
DEVI void transpose_body(const float* __restrict__ src, bf16_t* __restrict__ dst,
                         int R, int C, float scale, int tile, int t,
                         u16 (*tileb)[65]) {
  int tiles_c = C >> 6;
  int tc = tile % tiles_c;
  int tr = tile / tiles_c;
  int r0 = tr << 6, c0 = tc << 6;
  #pragma unroll
  for (int p = 0; p < 4; ++p) {
    int idx = t + p * 256;
    int i = idx >> 4, j4 = (idx & 15) * 4;
    float4 f = *(const float4*)(src + (size_t)(r0 + i) * C + c0 + j4);
    tileb[i][j4 + 0] = __builtin_bit_cast(u16, (bf16_t)(f.x * scale));
    tileb[i][j4 + 1] = __builtin_bit_cast(u16, (bf16_t)(f.y * scale));
    tileb[i][j4 + 2] = __builtin_bit_cast(u16, (bf16_t)(f.z * scale));
    tileb[i][j4 + 3] = __builtin_bit_cast(u16, (bf16_t)(f.w * scale));
  }
  __syncthreads();
  #pragma unroll
  for (int p = 0; p < 2; ++p) {
    int idx = t + p * 256;
    int j = idx >> 3, i0 = (idx & 7) * 8;
    u16 us[8];
    #pragma unroll
    for (int e = 0; e < 8; ++e) us[e] = tileb[i0 + e][j];
    uint4 o;
    o.x = (u32)us[0] | ((u32)us[1] << 16);
    o.y = (u32)us[2] | ((u32)us[3] << 16);
    o.z = (u32)us[4] | ((u32)us[5] << 16);
    o.w = (u32)us[6] | ((u32)us[7] << 16);
    *(uint4*)((u16*)dst + (size_t)(c0 + j) * R + r0 + i0) = o;
  }
}

__global__ __launch_bounds__(256) void k_prep(
    const float* __restrict__ qa, const float* __restrict__ ka, const float* __restrict__ va,
    const float* __restrict__ Wq, const float* __restrict__ Wk,
    const float* __restrict__ Wv, const float* __restrict__ Wo,
    bf16_t* __restrict__ Abf,
    bf16_t* __restrict__ WqT, bf16_t* __restrict__ WkT,
    bf16_t* __restrict__ WvT, bf16_t* __restrict__ WoT) {
  __shared__ u16 tileb[64][65];
  const int bid = blockIdx.x;
  const int t = threadIdx.x;
  if (bid < 3072) {
    int which = bid >> 10;
    int bb = bid & 1023;
    const float* s = which == 0 ? qa : which == 1 ? ka : va;
    u16* d = (u16*)Abf + (size_t)which * 8192 * 1024;
    size_t base = ((size_t)bb * 256 + t) * 8;
    #pragma unroll
    for (int p = 0; p < 4; ++p) {
      size_t i = base + (size_t)p * 2097152;
      float4 f0 = *(const float4*)(s + i);
      float4 f1 = *(const float4*)(s + i + 4);
      uint4 o;
      o.x = cvt_pk_bf16(f0.x, f0.y); o.y = cvt_pk_bf16(f0.z, f0.w);
      o.z = cvt_pk_bf16(f1.x, f1.y); o.w = cvt_pk_bf16(f1.z, f1.w);
      *(uint4*)(d + i) = o;
    }
  } else {
    int r = bid - 3072;
    if (r < 256)      transpose_body(Wq, WqT, 1024, 1024, QSCALE, r,       t, tileb);
    else if (r < 512) transpose_body(Wk, WkT, 1024, 1024, 1.0f,   r - 256, t, tileb);
    else if (r < 768) transpose_body(Wv, WvT, 1024, 1024, 1.0f,   r - 512, t, tileb);
    else              transpose_body(Wo, WoT, 1024, 64,   1.0f,   r - 768, t, tileb);
  }
}

// ---------------------------------------------------------------------------
// QKV projection GEMM. PRE=1: A pre-converted bf16, staged via global_load_lds.
// which==0/1 (q,k): epilogue scatters to (B,H,S,Dk). which==2 (v): epilogue
// writes vT (B,H,Dk,S) directly. BM=BN=128, BK=64. grid=3*512.
// ---------------------------------------------------------------------------
template<bool PRE>
__global__ __launch_bounds__(256) void k_proj_gemm(
    const float* __restrict__ Aq, const float* __restrict__ Ak, const float* __restrict__ Av,
    const bf16_t* __restrict__ Abf,
    const bf16_t* __restrict__ WqT, const bf16_t* __restrict__ WkT, const bf16_t* __restrict__ WvT,
    const float* __restrict__ bq, const float* __restrict__ bk, const float* __restrict__ bv,
    bf16_t* __restrict__ qh, bf16_t* __restrict__ kh, bf16_t* __restrict__ vT) {
  int bx = blockIdx.x;
  int which = bx >> 9;
  int tt = bx & 511;
  int tile_m = tt & 63;
  int tile_n = tt >> 6;
  const float* A    = which == 0 ? Aq : which == 1 ? Ak : Av;
  const bf16_t* Ab  = Abf + (size_t)which * 8192 * 1024;
  const bf16_t* WT  = which == 0 ? WqT : which == 1 ? WkT : WvT;
  const float* bias = which == 0 ? bq : which == 1 ? bk : bv;
  const float bscale = which == 0 ? QSCALE : 1.0f;

  const int t = threadIdx.x;
  const int l = t & 63;
  const int w = t >> 6;
  const int wm = w >> 1, wn = w & 1;
  const int c = l & 15, g = l >> 4;
  const int row0 = tile_m << 7;
  const int n0 = tile_n << 7;

  __shared__ __align__(16) char As[128 * 64 * 2];
  __shared__ __align__(16) char Bs[128 * 64 * 2];

  f32x4 acc[4][4];
  #pragma unroll
  for (int i = 0; i < 4; ++i)
    #pragma unroll
    for (int j = 0; j < 4; ++j) acc[i][j] = (f32x4){0.f, 0.f, 0.f, 0.f};

  // fallback A map: row = p*16 + (t>>4), fp32 col4 = (t&15)*4
  const int arow_b = t >> 4, ac4 = t & 15;
  const float* agbase = A + (size_t)(row0 + arow_b) * 1024 + ac4 * 4;
  char* aldst = As + arow_b * 128 + (((ac4 >> 1) ^ (arow_b & 7)) << 4) + (ac4 & 1) * 8;

  for (int kt = 0; kt < 16; ++kt) {
    __syncthreads();
    if constexpr (PRE) {
      #pragma unroll
      for (int cc = 0; cc < 4; ++cc) {
        int slot = w * 256 + cc * 64 + l;
        int row = slot >> 3, chs = slot & 7;
        const bf16_t* src = Ab + (size_t)(row0 + row) * 1024 + kt * 64 + ((chs ^ (row & 7)) << 3);
        gload_lds16(src, As + (w * 256 + cc * 64) * 16);
      }
    } else {
      const float* ap = agbase + kt * 64;
      #pragma unroll
      for (int p = 0; p < 8; ++p) {
        float4 f = *(const float4*)(ap + (size_t)p * 16384);
        uint2 o;
        o.x = cvt_pk_bf16(f.x, f.y);
        o.y = cvt_pk_bf16(f.z, f.w);
        *(uint2*)(aldst + p * 2048) = o;
      }
    }
    #pragma unroll
    for (int cc = 0; cc < 4; ++cc) {
      int slot = w * 256 + cc * 64 + l;
      int row = slot >> 3, chs = slot & 7;
      const bf16_t* src = WT + (size_t)(n0 + row) * 1024 + kt * 64 + ((chs ^ (row & 7)) << 3);
      gload_lds16(src, Bs + (w * 256 + cc * 64) * 16);
    }
    wait_vmcnt0();
    __syncthreads();
    #pragma unroll
    for (int kk = 0; kk < 2; ++kk) {
      bf16x8 af[4], bfr[4];
      #pragma unroll
      for (int mi = 0; mi < 4; ++mi) {
        int row = wm * 64 + mi * 16 + c;
        U16x8 u; u.u = *(const uint4*)(As + row * 128 + ((kk * 64 + g * 16) ^ ((c & 7) << 4)));
        af[mi] = u.v;
      }
      #pragma unroll
      for (int ni = 0; ni < 4; ++ni) {
        int row = wn * 64 + ni * 16 + c;
        U16x8 u; u.u = *(const uint4*)(Bs + row * 128 + ((kk * 64 + g * 16) ^ ((c & 7) << 4)));
        bfr[ni] = u.v;
      }
      #pragma unroll
      for (int mi = 0; mi < 4; ++mi)
        #pragma unroll
        for (int ni = 0; ni < 4; ++ni)
          acc[mi][ni] = __builtin_amdgcn_mfma_f32_16x16x32_bf16(af[mi], bfr[ni], acc[mi][ni], 0, 0, 0);
    }
  }

  const int b = row0 >> 11;
  const int sl0 = row0 & 2047;
  if (which == 2) {
    u16* vbase = (u16*)vT;
    #pragma unroll
    for (int ni = 0; ni < 4; ++ni) {
      int col = n0 + wn * 64 + ni * 16 + c;
      float bb = bias[col];
      int h = col >> 6, d = col & 63;
      u16* rowp = vbase + (((size_t)(b * 16 + h) * 64 + d) * 2048);
      #pragma unroll
      for (int mi = 0; mi < 4; ++mi) {
        int s = sl0 + wm * 64 + mi * 16 + g * 4;
        uint2 pv;
        pv.x = cvt_pk_bf16(acc[mi][ni][0] + bb, acc[mi][ni][1] + bb);
        pv.y = cvt_pk_bf16(acc[mi][ni][2] + bb, acc[mi][ni][3] + bb);
        *(uint2*)(rowp + s) = pv;
      }
    }
  } else {
    bf16_t* dst = which == 0 ? qh : kh;
    u16* dd = (u16*)dst;
    #pragma unroll
    for (int ni = 0; ni < 4; ++ni) {
      int col = n0 + wn * 64 + ni * 16 + c;
      float bb = bias[col] * bscale;
      int h = col >> 6, d = col & 63;
      #pragma unroll
      for (int mi = 0; mi < 4; ++mi) {
        #pragma unroll
        for (int r = 0; r < 4; ++r) {
          int s = sl0 + wm * 64 + mi * 16 + g * 4 + r;
          float vv = acc[mi][ni][r] + bb;
          size_t idx = (((size_t)b * 16 + h) * 2048 + s) * 64 + d;
          dd[idx] = __builtin_bit_cast(u16, (bf16_t)vv);
        }
      }
    }
  }
}

// ---------------------------------------------------------------------------
// Flash attention v9: KVBLK=128, 512 thr = 8 waves x 32 q = 256 q rows/block.
// 4x fewer barrier/vmcnt events per unit work vs v8 (16 kv-iters, 2x q/block).
// LDS 64KB dbuf -> 2 blocks/CU = 16 waves/CU (same occupancy as v8).
// P in-register (cvt_pk + permlane32_swap); denominator on MFMA pipe (ones).
// grid = 512 (XCD swizzle 8x64).
// ---------------------------------------------------------------------------
__global__ __launch_bounds__(512, 4) void k_attn(
    const bf16_t* __restrict__ qh, const bf16_t* __restrict__ kh,
    const bf16_t* __restrict__ vT, bf16_t* __restrict__ ctx) {
  const int bid = blockIdx.x;
  const int bx = ((bid & 7) << 6) | (bid >> 3);   // XCD swizzle: 512 = 8*64
  const int bh = bx >> 3;
  const int qt = bx & 7;
  const int q0 = qt << 8;                          // 256 q rows per block
  const int t = threadIdx.x, l = t & 63, w = t >> 6;  // w 0..7
  const int q = l & 31;
  const int hi = l >> 5;
  const int swz = (q & 7) << 4;

  __shared__ __align__(16) char Ks[2][128 * 128];  // [128 k'][128B]
  __shared__ __align__(16) char Vs[2][64 * 256];   // [64 d][256B]

  // Q^T B-frags: lane holds Q[q0+w*32+q][ks*16 + hi*8 + j], ks = 0..3
  const u16* qrow = (const u16*)qh + ((size_t)bh * 2048 + q0 + w * 32 + q) * 64;
  bf16x8 qf0, qf1, qf2, qf3;
  {
    U16x8 u;
    u.u = *(const uint4*)(qrow + 0 * 16 + hi * 8); qf0 = u.v;
    u.u = *(const uint4*)(qrow + 1 * 16 + hi * 8); qf1 = u.v;
    u.u = *(const uint4*)(qrow + 2 * 16 + hi * 8); qf2 = u.v;
    u.u = *(const uint4*)(qrow + 3 * 16 + hi * 8); qf3 = u.v;
  }

  bf16x8 ones;
  {
    U16x8 u;
    u.u = (uint4){0x3F803F80u, 0x3F803F80u, 0x3F803F80u, 0x3F803F80u};
    ones = u.v;
  }

  const f32x16 z16 = {0.f,0.f,0.f,0.f, 0.f,0.f,0.f,0.f, 0.f,0.f,0.f,0.f, 0.f,0.f,0.f,0.f};
  f32x16 oc0 = z16, oc1 = z16, psum = z16;

  const u16* kbh = (const u16*)kh + (size_t)bh * 2048 * 64;
  const u16* vbh = (const u16*)vT + (size_t)bh * 64 * 2048;

  // staging: K = 1024 16B-slots over [128][128B]; V = 1024 slots over [64][256B].
  // 512 threads -> 2 K + 2 V slots each; LDS dest linear (wave-uniform + lane*16).
  auto stage = [&](int kvi, int buf) {
    int kbase = kvi << 7;
    #pragma unroll
    for (int cc = 0; cc < 2; ++cc) {
      int slot = cc * 512 + t;
      {
        int row = slot >> 3, chs = slot & 7;
        gload_lds16(kbh + (size_t)(kbase + row) * 64 + ((chs ^ (row & 7)) << 3),
                    Ks[buf] + (cc * 512 + w * 64) * 16);
      }
      {
        int row = slot >> 4, chs = slot & 15;
        int chsw = (chs & 8) | ((chs & 7) ^ (row & 7));
        gload_lds16(vbh + (size_t)row * 2048 + kbase + (chsw << 3),
                    Vs[buf] + (cc * 512 + w * 64) * 16);
      }
    }
  };

  stage(0, 0);
  wait_vmcnt0();
  __syncthreads();

  for (int kv = 0; kv < 16; ++kv) {
    const int cur = kv & 1;
    if (kv < 15) stage(kv + 1, cur ^ 1);          // issue-early prefetch
    const char* Kc = Ks[cur];
    const char* Vc = Vs[cur];

    #pragma unroll
    for (int tt = 0; tt < 4; ++tt) {
      // ---- QK^T: S^T[k' = tt*32 + 8qd+4hi+r][q], log2 units ----
      const int arow = tt * 32 + q;
      f32x16 st = z16;
      __builtin_amdgcn_s_setprio(1);
      st = mfma32(lds_frag<128>(Kc, arow, 0 * 32 + hi * 16, swz), qf0, st);
      st = mfma32(lds_frag<128>(Kc, arow, 1 * 32 + hi * 16, swz), qf1, st);
      st = mfma32(lds_frag<128>(Kc, arow, 2 * 32 + hi * 16, swz), qf2, st);
      st = mfma32(lds_frag<128>(Kc, arow, 3 * 32 + hi * 16, swz), qf3, st);
      __builtin_amdgcn_s_setprio(0);

      // ---- softmax numerators (no max): exp2 ----
      float e[16];
      #pragma unroll
      for (int i = 0; i < 16; ++i) e[i] = __builtin_amdgcn_exp2f(st[i]);

      // ---- P -> A-frags in-register; PV + denom ----
      #pragma unroll
      for (int cc = 0; cc < 2; ++cc) {
        u32 a  = cvt_pk_bf16(e[8 * cc + 0], e[8 * cc + 1]);
        u32 b  = cvt_pk_bf16(e[8 * cc + 4], e[8 * cc + 5]);
        u32 c2 = cvt_pk_bf16(e[8 * cc + 2], e[8 * cc + 3]);
        u32 d  = cvt_pk_bf16(e[8 * cc + 6], e[8 * cc + 7]);
        permswap(a, b);
        permswap(c2, d);
        PU pu;
        pu.w[0] = a; pu.w[1] = c2; pu.w[2] = b; pu.w[3] = d;
        const int ks = tt * 2 + cc;                // 16-k chunk, 0..7
        const int koff = ks * 32 + hi * 16;        // 0..240 within 256B V row
        __builtin_amdgcn_s_setprio(1);
        oc0 = mfma32(pu.v, lds_frag<256>(Vc, q,      koff, swz), oc0);
        oc1 = mfma32(pu.v, lds_frag<256>(Vc, 32 + q, koff, swz), oc1);
        psum = mfma32(pu.v, ones, psum);
        __builtin_amdgcn_s_setprio(0);
      }
    }
    wait_vmcnt0();      // next tile's staging landed
    __syncthreads();
  }

  // ---- epilogue: per-lane normalize (psum rows match oc rows), store bf16 ----
  const int b = bh >> 4, hh = bh & 15;
  u16* cb = (u16*)ctx;
  #pragma unroll
  for (int qd = 0; qd < 4; ++qd) {
    #pragma unroll
    for (int r = 0; r < 4; ++r) {
      float inv = 1.f / psum[qd * 4 + r];
      int qrow_g = q0 + w * 32 + qd * 8 + hi * 4 + r;
      size_t base = ((size_t)b * 2048 + qrow_g) * 1024 + hh * 64;
      float v0 = oc0[qd * 4 + r] * inv;
      float v1 = oc1[qd * 4 + r] * inv;
      cb[base + q]      = __builtin_bit_cast(u16, (bf16_t)v0);
      cb[base + 32 + q] = __builtin_bit_cast(u16, (bf16_t)v1);
    }
  }
}

// ---------------------------------------------------------------------------
// Output projection: out[8192,64] = ctx(bf16) @ Wo + bo (fp32 out).
// BM=32, BN=64, BK=64 -> grid = 256. 4 waves as 2x2.
// ---------------------------------------------------------------------------
__global__ __launch_bounds__(256) void k_out_gemm(
    const bf16_t* __restrict__ ctx, const bf16_t* __restrict__ WoT,
    const float* __restrict__ bo, float* __restrict__ out) {
  int tile_m = blockIdx.x;
  const int t = threadIdx.x, l = t & 63, w = t >> 6;
  const int wm = w >> 1, wn = w & 1;
  const int c = l & 15, g = l >> 4;
  const int row0 = tile_m << 5;

  __shared__ __align__(16) char As[32 * 64 * 2];
  __shared__ __align__(16) char Bs[64 * 64 * 2];

  f32x4 acc[2];
  acc[0] = (f32x4){0.f, 0.f, 0.f, 0.f};
  acc[1] = (f32x4){0.f, 0.f, 0.f, 0.f};

  for (int kt = 0; kt < 16; ++kt) {
    __syncthreads();
    {
      int row = t >> 3, chs = t & 7;
      const bf16_t* src = ctx + (size_t)(row0 + row) * 1024 + kt * 64 + ((chs ^ (row & 7)) << 3);
      gload_lds16(src, As + t * 16);
    }
    #pragma unroll
    for (int cc = 0; cc < 2; ++cc) {
      int slot = w * 128 + cc * 64 + l;
      int row = slot >> 3, chs = slot & 7;
      const bf16_t* src = WoT + (size_t)row * 1024 + kt * 64 + ((chs ^ (row & 7)) << 3);
      gload_lds16(src, Bs + (w * 128 + cc * 64) * 16);
    }
    wait_vmcnt0();
    __syncthreads();
    #pragma unroll
    for (int kk = 0; kk < 2; ++kk) {
      bf16x8 af;
      {
        int row = wm * 16 + c;
        U16x8 u; u.u = *(const uint4*)(As + row * 128 + ((kk * 64 + g * 16) ^ ((c & 7) << 4)));
        af = u.v;
      }
      #pragma unroll
      for (int ni = 0; ni < 2; ++ni) {
        int row = wn * 32 + ni * 16 + c;
        U16x8 u; u.u = *(const uint4*)(Bs + row * 128 + ((kk * 64 + g * 16) ^ ((c & 7) << 4)));
        acc[ni] = __builtin_amdgcn_mfma_f32_16x16x32_bf16(af, u.v, acc[ni], 0, 0, 0);
      }
    }
  }
  #pragma unroll
  for (int ni = 0; ni < 2; ++ni) {
    int col = wn * 32 + ni * 16 + c;
    float bb = bo[col];
    #pragma unroll
    for (int r = 0; r < 4; ++r) {
      int rowg = row0 + wm * 16 + g * 4 + r;
      out[(size_t)rowg * 64 + col] = acc[ni][r] + bb;
    }
  }
}

// ---------------------------------------------------------------------------
extern "C" void kernel_launch(void* const* d_in, const int* in_sizes, int n_in,
                              void* d_out, int out_size, void* d_ws, size_t ws_size,
                              hipStream_t stream) {
  (void)in_sizes; (void)n_in; (void)out_size;
  const float* query = (const float*)d_in[0];
  const float* key_  = (const float*)d_in[1];
  const float* value = (const float*)d_in[2];
  const float* Wq = (const float*)d_in[3];
  const float* bq = (const float*)d_in[4];
  const float* Wk = (const float*)d_in[5];
  const float* bk = (const float*)d_in[6];
  const float* Wv = (const float*)d_in[7];
  const float* bv = (const float*)d_in[8];
  const float* Wo = (const float*)d_in[9];
  const float* bo = (const float*)d_in[10];
  float* out = (float*)d_out;

  char* ws = (char*)d_ws;
  bf16_t* WqT = (bf16_t*)(ws + (size_t)0);
  bf16_t* WkT = (bf16_t*)(ws + ((size_t)2 << 20));
  bf16_t* WvT = (bf16_t*)(ws + ((size_t)4 << 20));
  bf16_t* WoT = (bf16_t*)(ws + ((size_t)6 << 20));
  bf16_t* qhd = (bf16_t*)(ws + ((size_t)8 << 20));
  bf16_t* khd = (bf16_t*)(ws + ((size_t)24 << 20));
  bf16_t* vT  = (bf16_t*)(ws + ((size_t)56 << 20));
  bf16_t* ctx = (bf16_t*)(ws + ((size_t)72 << 20));
  bf16_t* Abf = (bf16_t*)(ws + ((size_t)88 << 20));

  const bool pre = ws_size >= ((size_t)137 << 20);

  k_prep<<<3856, 256, 0, stream>>>(query, key_, value, Wq, Wk, Wv, Wo,
                                   Abf, WqT, WkT, WvT, WoT);
  if (pre) {
    k_proj_gemm<true><<<1536, 256, 0, stream>>>(query, key_, value, Abf, WqT, WkT, WvT,
                                                bq, bk, bv, qhd, khd, vT);
  } else {
    k_proj_gemm<false><<<1536, 256, 0, stream>>>(query, key_, value, Abf, WqT, WkT, WvT,
                                                 bq, bk, bv, qhd, khd, vT);
  }
  k_attn<<<512, 512, 0, stream>>>(qhd, khd, vT, ctx);
  k_out_gemm<<<256, 256, 0, stream>>>(ctx, WoT, bo, out);
}

// Round 16
// 180.100 us; speedup vs baseline: 1.5918x; 1.0016x over previous
//
#include <hip/hip_runtime.h>
#include <hip/hip_bf16.h>
#include <cstdint>
#include <cstddef>

#define DEVI static __device__ __forceinline__

typedef unsigned short u16;
typedef unsigned int u32;
typedef __bf16 bf16_t;
typedef __bf16 bf16x8 __attribute__((ext_vector_type(8)));
typedef float f32x4 __attribute__((ext_vector_type(4)));
typedef float f32x16 __attribute__((ext_vector_type(16)));

union U16x8 { uint4 u; bf16x8 v; };
union PU { u32 w[4]; bf16x8 v; };

// 0.125 (1/sqrt(64)) * log2(e): folded into Wq/bq so scores are log2-scaled.
#define QSCALE 0.1803368801111204f

DEVI void gload_lds16(const void* g, void* l) {
  __builtin_amdgcn_global_load_lds((const __attribute__((address_space(1))) void*)g,
                                   (__attribute__((address_space(3))) void*)l, 16, 0, 0);
}
DEVI void wait_vmcnt0() { asm volatile("s_waitcnt vmcnt(0)" ::: "memory"); }

DEVI u32 cvt_pk_bf16(float lo, float hi) {
  u32 r;
  asm("v_cvt_pk_bf16_f32 %0, %1, %2" : "=v"(r) : "v"(lo), "v"(hi));
  return r;
}

// exchange: a's high-32-lane slice <-> b's low-32-lane slice
DEVI void permswap(u32& a, u32& b) {
  asm("v_permlane32_swap_b32 %0, %1" : "+v"(a), "+v"(b));
}

DEVI f32x16 mfma32(bf16x8 a, bf16x8 b, f32x16 c) {
  return __builtin_amdgcn_mfma_f32_32x32x16_bf16(a, b, c, 0, 0, 0);
}

// read one swizzled 16B fragment; row stride templated (128B K rows, 256B V rows)
template<int STRIDE>
DEVI bf16x8 lds_frag(const char* base, int row, int koff, int swz) {
  U16x8 u;
  u.u = *(const uint4*)(base + row * STRIDE + (koff ^ swz));
  return u.v;
}

// ---------------------------------------------------------------------------
// Merged preprocessing: blocks [0,3072): fp32->bf16 convert of q/k/v;
// blocks [3072,3840): weight transposes Wq/Wk/Wv; [3840,3856): Wo.
// ---------------------------------------------------------------------------
DEVI void transpose_body(const float* __restrict__ src, bf16_t* __restrict__ dst,
                         int R, int C, float scale, int tile, int t,
                         u16 (*tileb)[65]) {
  int tiles_c = C >> 6;
  int tc = tile % tiles_c;
  int tr = tile / tiles_c;
  int r0 = tr << 6, c0 = tc << 6;
  #pragma unroll
  for (int p = 0; p < 4; ++p) {
    int idx = t + p * 256;
    int i = idx >> 4, j4 = (idx & 15) * 4;
    float4 f = *(const float4*)(src + (size_t)(r0 + i) * C + c0 + j4);
    tileb[i][j4 + 0] = __builtin_bit_cast(u16, (bf16_t)(f.x * scale));
    tileb[i][j4 + 1] = __builtin_bit_cast(u16, (bf16_t)(f.y * scale));
    tileb[i][j4 + 2] = __builtin_bit_cast(u16, (bf16_t)(f.z * scale));
    tileb[i][j4 + 3] = __builtin_bit_cast(u16, (bf16_t)(f.w * scale));
  }
  __syncthreads();
  #pragma unroll
  for (int p = 0; p < 2; ++p) {
    int idx = t + p * 256;
    int j = idx >> 3, i0 = (idx & 7) * 8;
    u16 us[8];
    #pragma unroll
    for (int e = 0; e < 8; ++e) us[e] = tileb[i0 + e][j];
    uint4 o;
    o.x = (u32)us[0] | ((u32)us[1] << 16);
    o.y = (u32)us[2] | ((u32)us[3] << 16);
    o.z = (u32)us[4] | ((u32)us[5] << 16);
    o.w = (u32)us[6] | ((u32)us[7] << 16);
    *(uint4*)((u16*)dst + (size_t)(c0 + j) * R + r0 + i0) = o;
  }
}

__global__ __launch_bounds__(256) void k_prep(
    const float* __restrict__ qa, const float* __restrict__ ka, const float* __restrict__ va,
    const float* __restrict__ Wq, const float* __restrict__ Wk,
    const float* __restrict__ Wv, const float* __restrict__ Wo,
    bf16_t* __restrict__ Abf,
    bf16_t* __restrict__ WqT, bf16_t* __restrict__ WkT,
    bf16_t* __restrict__ WvT, bf16_t* __restrict__ WoT) {
  __shared__ u16 tileb[64][65];
  const int bid = blockIdx.x;
  const int t = threadIdx.x;
  if (bid < 3072) {
    int which = bid >> 10;
    int bb = bid & 1023;
    const float* s = which == 0 ? qa : which == 1 ? ka : va;
    u16* d = (u16*)Abf + (size_t)which * 8192 * 1024;
    size_t base = ((size_t)bb * 256 + t) * 8;
    #pragma unroll
    for (int p = 0; p < 4; ++p) {
      size_t i = base + (size_t)p * 2097152;
      float4 f0 = *(const float4*)(s + i);
      float4 f1 = *(const float4*)(s + i + 4);
      uint4 o;
      o.x = cvt_pk_bf16(f0.x, f0.y); o.y = cvt_pk_bf16(f0.z, f0.w);
      o.z = cvt_pk_bf16(f1.x, f1.y); o.w = cvt_pk_bf16(f1.z, f1.w);
      *(uint4*)(d + i) = o;
    }
  } else {
    int r = bid - 3072;
    if (r < 256)      transpose_body(Wq, WqT, 1024, 1024, QSCALE, r,       t, tileb);
    else if (r < 512) transpose_body(Wk, WkT, 1024, 1024, 1.0f,   r - 256, t, tileb);
    else if (r < 768) transpose_body(Wv, WvT, 1024, 1024, 1.0f,   r - 512, t, tileb);
    else              transpose_body(Wo, WoT, 1024, 64,   1.0f,   r - 768, t, tileb);
  }
}

// ---------------------------------------------------------------------------
// QKV projection GEMM. PRE=1: A pre-converted bf16, staged via global_load_lds.
// which==0/1 (q,k): epilogue scatters to (B,H,S,Dk). which==2 (v): epilogue
// writes vT (B,H,Dk,S) directly. BM=BN=128, BK=64. grid=3*512.
// ---------------------------------------------------------------------------
template<bool PRE>
__global__ __launch_bounds__(256) void k_proj_gemm(
    const float* __restrict__ Aq, const float* __restrict__ Ak, const float* __restrict__ Av,
    const bf16_t* __restrict__ Abf,
    const bf16_t* __restrict__ WqT, const bf16_t* __restrict__ WkT, const bf16_t* __restrict__ WvT,
    const float* __restrict__ bq, const float* __restrict__ bk, const float* __restrict__ bv,
    bf16_t* __restrict__ qh, bf16_t* __restrict__ kh, bf16_t* __restrict__ vT) {
  int bx = blockIdx.x;
  int which = bx >> 9;
  int tt = bx & 511;
  int tile_m = tt & 63;
  int tile_n = tt >> 6;
  const float* A    = which == 0 ? Aq : which == 1 ? Ak : Av;
  const bf16_t* Ab  = Abf + (size_t)which * 8192 * 1024;
  const bf16_t* WT  = which == 0 ? WqT : which == 1 ? WkT : WvT;
  const float* bias = which == 0 ? bq : which == 1 ? bk : bv;
  const float bscale = which == 0 ? QSCALE : 1.0f;

  const int t = threadIdx.x;
  const int l = t & 63;
  const int w = t >> 6;
  const int wm = w >> 1, wn = w & 1;
  const int c = l & 15, g = l >> 4;
  const int row0 = tile_m << 7;
  const int n0 = tile_n << 7;

  __shared__ __align__(16) char As[128 * 64 * 2];
  __shared__ __align__(16) char Bs[128 * 64 * 2];

  f32x4 acc[4][4];
  #pragma unroll
  for (int i = 0; i < 4; ++i)
    #pragma unroll
    for (int j = 0; j < 4; ++j) acc[i][j] = (f32x4){0.f, 0.f, 0.f, 0.f};

  // fallback A map: row = p*16 + (t>>4), fp32 col4 = (t&15)*4
  const int arow_b = t >> 4, ac4 = t & 15;
  const float* agbase = A + (size_t)(row0 + arow_b) * 1024 + ac4 * 4;
  char* aldst = As + arow_b * 128 + (((ac4 >> 1) ^ (arow_b & 7)) << 4) + (ac4 & 1) * 8;

  for (int kt = 0; kt < 16; ++kt) {
    __syncthreads();
    if constexpr (PRE) {
      #pragma unroll
      for (int cc = 0; cc < 4; ++cc) {
        int slot = w * 256 + cc * 64 + l;
        int row = slot >> 3, chs = slot & 7;
        const bf16_t* src = Ab + (size_t)(row0 + row) * 1024 + kt * 64 + ((chs ^ (row & 7)) << 3);
        gload_lds16(src, As + (w * 256 + cc * 64) * 16);
      }
    } else {
      const float* ap = agbase + kt * 64;
      #pragma unroll
      for (int p = 0; p < 8; ++p) {
        float4 f = *(const float4*)(ap + (size_t)p * 16384);
        uint2 o;
        o.x = cvt_pk_bf16(f.x, f.y);
        o.y = cvt_pk_bf16(f.z, f.w);
        *(uint2*)(aldst + p * 2048) = o;
      }
    }
    #pragma unroll
    for (int cc = 0; cc < 4; ++cc) {
      int slot = w * 256 + cc * 64 + l;
      int row = slot >> 3, chs = slot & 7;
      const bf16_t* src = WT + (size_t)(n0 + row) * 1024 + kt * 64 + ((chs ^ (row & 7)) << 3);
      gload_lds16(src, Bs + (w * 256 + cc * 64) * 16);
    }
    wait_vmcnt0();
    __syncthreads();
    #pragma unroll
    for (int kk = 0; kk < 2; ++kk) {
      bf16x8 af[4], bfr[4];
      #pragma unroll
      for (int mi = 0; mi < 4; ++mi) {
        int row = wm * 64 + mi * 16 + c;
        U16x8 u; u.u = *(const uint4*)(As + row * 128 + ((kk * 64 + g * 16) ^ ((c & 7) << 4)));
        af[mi] = u.v;
      }
      #pragma unroll
      for (int ni = 0; ni < 4; ++ni) {
        int row = wn * 64 + ni * 16 + c;
        U16x8 u; u.u = *(const uint4*)(Bs + row * 128 + ((kk * 64 + g * 16) ^ ((c & 7) << 4)));
        bfr[ni] = u.v;
      }
      #pragma unroll
      for (int mi = 0; mi < 4; ++mi)
        #pragma unroll
        for (int ni = 0; ni < 4; ++ni)
          acc[mi][ni] = __builtin_amdgcn_mfma_f32_16x16x32_bf16(af[mi], bfr[ni], acc[mi][ni], 0, 0, 0);
    }
  }

  const int b = row0 >> 11;
  const int sl0 = row0 & 2047;
  if (which == 2) {
    u16* vbase = (u16*)vT;
    #pragma unroll
    for (int ni = 0; ni < 4; ++ni) {
      int col = n0 + wn * 64 + ni * 16 + c;
      float bb = bias[col];
      int h = col >> 6, d = col & 63;
      u16* rowp = vbase + (((size_t)(b * 16 + h) * 64 + d) * 2048);
      #pragma unroll
      for (int mi = 0; mi < 4; ++mi) {
        int s = sl0 + wm * 64 + mi * 16 + g * 4;
        uint2 pv;
        pv.x = cvt_pk_bf16(acc[mi][ni][0] + bb, acc[mi][ni][1] + bb);
        pv.y = cvt_pk_bf16(acc[mi][ni][2] + bb, acc[mi][ni][3] + bb);
        *(uint2*)(rowp + s) = pv;
      }
    }
  } else {
    bf16_t* dst = which == 0 ? qh : kh;
    u16* dd = (u16*)dst;
    #pragma unroll
    for (int ni = 0; ni < 4; ++ni) {
      int col = n0 + wn * 64 + ni * 16 + c;
      float bb = bias[col] * bscale;
      int h = col >> 6, d = col & 63;
      #pragma unroll
      for (int mi = 0; mi < 4; ++mi) {
        #pragma unroll
        for (int r = 0; r < 4; ++r) {
          int s = sl0 + wm * 64 + mi * 16 + g * 4 + r;
          float vv = acc[mi][ni][r] + bb;
          size_t idx = (((size_t)b * 16 + h) * 2048 + s) * 64 + d;
          dd[idx] = __builtin_bit_cast(u16, (bf16_t)vv);
        }
      }
    }
  }
}

// ---------------------------------------------------------------------------
// Flash attention v9: KVBLK=128, 512 thr = 8 waves x 32 q = 256 q rows/block.
// LDS 64KB dbuf -> 2 blocks/CU = 16 waves/CU. P in-register (cvt_pk +
// permlane32_swap); denominator on MFMA pipe (ones). grid = 512 (XCD swizzle).
// ---------------------------------------------------------------------------
__global__ __launch_bounds__(512, 4) void k_attn(
    const bf16_t* __restrict__ qh, const bf16_t* __restrict__ kh,
    const bf16_t* __restrict__ vT, bf16_t* __restrict__ ctx) {
  const int bid = blockIdx.x;
  const int bx = ((bid & 7) << 6) | (bid >> 3);   // XCD swizzle: 512 = 8*64
  const int bh = bx >> 3;
  const int qt = bx & 7;
  const int q0 = qt << 8;                          // 256 q rows per block
  const int t = threadIdx.x, l = t & 63, w = t >> 6;  // w 0..7
  const int q = l & 31;
  const int hi = l >> 5;
  const int swz = (q & 7) << 4;

  __shared__ __align__(16) char Ks[2][128 * 128];  // [128 k'][128B]
  __shared__ __align__(16) char Vs[2][64 * 256];   // [64 d][256B]

  // Q^T B-frags: lane holds Q[q0+w*32+q][ks*16 + hi*8 + j], ks = 0..3
  const u16* qrow = (const u16*)qh + ((size_t)bh * 2048 + q0 + w * 32 + q) * 64;
  bf16x8 qf0, qf1, qf2, qf3;
  {
    U16x8 u;
    u.u = *(const uint4*)(qrow + 0 * 16 + hi * 8); qf0 = u.v;
    u.u = *(const uint4*)(qrow + 1 * 16 + hi * 8); qf1 = u.v;
    u.u = *(const uint4*)(qrow + 2 * 16 + hi * 8); qf2 = u.v;
    u.u = *(const uint4*)(qrow + 3 * 16 + hi * 8); qf3 = u.v;
  }

  bf16x8 ones;
  {
    U16x8 u;
    u.u = (uint4){0x3F803F80u, 0x3F803F80u, 0x3F803F80u, 0x3F803F80u};
    ones = u.v;
  }

  const f32x16 z16 = {0.f,0.f,0.f,0.f, 0.f,0.f,0.f,0.f, 0.f,0.f,0.f,0.f, 0.f,0.f,0.f,0.f};
  f32x16 oc0 = z16, oc1 = z16, psum = z16;

  const u16* kbh = (const u16*)kh + (size_t)bh * 2048 * 64;
  const u16* vbh = (const u16*)vT + (size_t)bh * 64 * 2048;

  // staging: K = 1024 16B-slots over [128][128B]; V = 1024 slots over [64][256B].
  // 512 threads -> 2 K + 2 V slots each; LDS dest linear (wave-uniform + lane*16).
  auto stage = [&](int kvi, int buf) {
    int kbase = kvi << 7;
    #pragma unroll
    for (int cc = 0; cc < 2; ++cc) {
      int slot = cc * 512 + t;
      {
        int row = slot >> 3, chs = slot & 7;
        gload_lds16(kbh + (size_t)(kbase + row) * 64 + ((chs ^ (row & 7)) << 3),
                    Ks[buf] + (cc * 512 + w * 64) * 16);
      }
      {
        int row = slot >> 4, chs = slot & 15;
        int chsw = (chs & 8) | ((chs & 7) ^ (row & 7));
        gload_lds16(vbh + (size_t)row * 2048 + kbase + (chsw << 3),
                    Vs[buf] + (cc * 512 + w * 64) * 16);
      }
    }
  };

  stage(0, 0);
  wait_vmcnt0();
  __syncthreads();

  for (int kv = 0; kv < 16; ++kv) {
    const int cur = kv & 1;
    if (kv < 15) stage(kv + 1, cur ^ 1);          // issue-early prefetch
    const char* Kc = Ks[cur];
    const char* Vc = Vs[cur];

    #pragma unroll
    for (int tt = 0; tt < 4; ++tt) {
      // ---- QK^T: S^T[k' = tt*32 + 8qd+4hi+r][q], log2 units ----
      const int arow = tt * 32 + q;
      f32x16 st = z16;
      __builtin_amdgcn_s_setprio(1);
      st = mfma32(lds_frag<128>(Kc, arow, 0 * 32 + hi * 16, swz), qf0, st);
      st = mfma32(lds_frag<128>(Kc, arow, 1 * 32 + hi * 16, swz), qf1, st);
      st = mfma32(lds_frag<128>(Kc, arow, 2 * 32 + hi * 16, swz), qf2, st);
      st = mfma32(lds_frag<128>(Kc, arow, 3 * 32 + hi * 16, swz), qf3, st);
      __builtin_amdgcn_s_setprio(0);

      // ---- softmax numerators (no max): exp2 ----
      float e[16];
      #pragma unroll
      for (int i = 0; i < 16; ++i) e[i] = __builtin_amdgcn_exp2f(st[i]);

      // ---- P -> A-frags in-register; PV + denom ----
      #pragma unroll
      for (int cc = 0; cc < 2; ++cc) {
        u32 a  = cvt_pk_bf16(e[8 * cc + 0], e[8 * cc + 1]);
        u32 b  = cvt_pk_bf16(e[8 * cc + 4], e[8 * cc + 5]);
        u32 c2 = cvt_pk_bf16(e[8 * cc + 2], e[8 * cc + 3]);
        u32 d  = cvt_pk_bf16(e[8 * cc + 6], e[8 * cc + 7]);
        permswap(a, b);
        permswap(c2, d);
        PU pu;
        pu.w[0] = a; pu.w[1] = c2; pu.w[2] = b; pu.w[3] = d;
        const int ks = tt * 2 + cc;                // 16-k chunk, 0..7
        const int koff = ks * 32 + hi * 16;        // 0..240 within 256B V row
        __builtin_amdgcn_s_setprio(1);
        oc0 = mfma32(pu.v, lds_frag<256>(Vc, q,      koff, swz), oc0);
        oc1 = mfma32(pu.v, lds_frag<256>(Vc, 32 + q, koff, swz), oc1);
        psum = mfma32(pu.v, ones, psum);
        __builtin_amdgcn_s_setprio(0);
      }
    }
    wait_vmcnt0();      // next tile's staging landed
    __syncthreads();
  }

  // ---- epilogue: per-lane normalize (psum rows match oc rows), store bf16 ----
  const int b = bh >> 4, hh = bh & 15;
  u16* cb = (u16*)ctx;
  #pragma unroll
  for (int qd = 0; qd < 4; ++qd) {
    #pragma unroll
    for (int r = 0; r < 4; ++r) {
      float inv = 1.f / psum[qd * 4 + r];
      int qrow_g = q0 + w * 32 + qd * 8 + hi * 4 + r;
      size_t base = ((size_t)b * 2048 + qrow_g) * 1024 + hh * 64;
      float v0 = oc0[qd * 4 + r] * inv;
      float v1 = oc1[qd * 4 + r] * inv;
      cb[base + q]      = __builtin_bit_cast(u16, (bf16_t)v0);
      cb[base + 32 + q] = __builtin_bit_cast(u16, (bf16_t)v1);
    }
  }
}

// ---------------------------------------------------------------------------
// Output projection: out[8192,64] = ctx(bf16) @ Wo + bo (fp32 out).
// BM=32, BN=64, BK=64 -> grid = 256. 4 waves as 2x2.
// ---------------------------------------------------------------------------
__global__ __launch_bounds__(256) void k_out_gemm(
    const bf16_t* __restrict__ ctx, const bf16_t* __restrict__ WoT,
    const float* __restrict__ bo, float* __restrict__ out) {
  int tile_m = blockIdx.x;
  const int t = threadIdx.x, l = t & 63, w = t >> 6;
  const int wm = w >> 1, wn = w & 1;
  const int c = l & 15, g = l >> 4;
  const int row0 = tile_m << 5;

  __shared__ __align__(16) char As[32 * 64 * 2];
  __shared__ __align__(16) char Bs[64 * 64 * 2];

  f32x4 acc[2];
  acc[0] = (f32x4){0.f, 0.f, 0.f, 0.f};
  acc[1] = (f32x4){0.f, 0.f, 0.f, 0.f};

  for (int kt = 0; kt < 16; ++kt) {
    __syncthreads();
    {
      int row = t >> 3, chs = t & 7;
      const bf16_t* src = ctx + (size_t)(row0 + row) * 1024 + kt * 64 + ((chs ^ (row & 7)) << 3);
      gload_lds16(src, As + t * 16);
    }
    #pragma unroll
    for (int cc = 0; cc < 2; ++cc) {
      int slot = w * 128 + cc * 64 + l;
      int row = slot >> 3, chs = slot & 7;
      const bf16_t* src = WoT + (size_t)row * 1024 + kt * 64 + ((chs ^ (row & 7)) << 3);
      gload_lds16(src, Bs + (w * 128 + cc * 64) * 16);
    }
    wait_vmcnt0();
    __syncthreads();
    #pragma unroll
    for (int kk = 0; kk < 2; ++kk) {
      bf16x8 af;
      {
        int row = wm * 16 + c;
        U16x8 u; u.u = *(const uint4*)(As + row * 128 + ((kk * 64 + g * 16) ^ ((c & 7) << 4)));
        af = u.v;
      }
      #pragma unroll
      for (int ni = 0; ni < 2; ++ni) {
        int row = wn * 32 + ni * 16 + c;
        U16x8 u; u.u = *(const uint4*)(Bs + row * 128 + ((kk * 64 + g * 16) ^ ((c & 7) << 4)));
        acc[ni] = __builtin_amdgcn_mfma_f32_16x16x32_bf16(af, u.v, acc[ni], 0, 0, 0);
      }
    }
  }
  #pragma unroll
  for (int ni = 0; ni < 2; ++ni) {
    int col = wn * 32 + ni * 16 + c;
    float bb = bo[col];
    #pragma unroll
    for (int r = 0; r < 4; ++r) {
      int rowg = row0 + wm * 16 + g * 4 + r;
      out[(size_t)rowg * 64 + col] = acc[ni][r] + bb;
    }
  }
}

// ---------------------------------------------------------------------------
extern "C" void kernel_launch(void* const* d_in, const int* in_sizes, int n_in,
                              void* d_out, int out_size, void* d_ws, size_t ws_size,
                              hipStream_t stream) {
  (void)in_sizes; (void)n_in; (void)out_size;
  const float* query = (const float*)d_in[0];
  const float* key_  = (const float*)d_in[1];
  const float* value = (const float*)d_in[2];
  const float* Wq = (const float*)d_in[3];
  const float* bq = (const float*)d_in[4];
  const float* Wk = (const float*)d_in[5];
  const float* bk = (const float*)d_in[6];
  const float* Wv = (const float*)d_in[7];
  const float* bv = (const float*)d_in[8];
  const float* Wo = (const float*)d_in[9];
  const float* bo = (const float*)d_in[10];
  float* out = (float*)d_out;

  char* ws = (char*)d_ws;
  bf16_t* WqT = (bf16_t*)(ws + (size_t)0);
  bf16_t* WkT = (bf16_t*)(ws + ((size_t)2 << 20));
  bf16_t* WvT = (bf16_t*)(ws + ((size_t)4 << 20));
  bf16_t* WoT = (bf16_t*)(ws + ((size_t)6 << 20));
  bf16_t* qhd = (bf16_t*)(ws + ((size_t)8 << 20));
  bf16_t* khd = (bf16_t*)(ws + ((size_t)24 << 20));
  bf16_t* vT  = (bf16_t*)(ws + ((size_t)56 << 20));
  bf16_t* ctx = (bf16_t*)(ws + ((size_t)72 << 20));
  bf16_t* Abf = (bf16_t*)(ws + ((size_t)88 << 20));

  const bool pre = ws_size >= ((size_t)137 << 20);

  k_prep<<<3856, 256, 0, stream>>>(query, key_, value, Wq, Wk, Wv, Wo,
                                   Abf, WqT, WkT, WvT, WoT);
  if (pre) {
    k_proj_gemm<true><<<1536, 256, 0, stream>>>(query, key_, value, Abf, WqT, WkT, WvT,
                                                bq, bk, bv, qhd, khd, vT);
  } else {
    k_proj_gemm<false><<<1536, 256, 0, stream>>>(query, key_, value, Abf, WqT, WkT, WvT,
                                                 bq, bk, bv, qhd, khd, vT);
  }
  k_attn<<<512, 512, 0, stream>>>(qhd, khd, vT, ctx);
  k_out_gemm<<<256, 256, 0, stream>>>(ctx, WoT, bo, out);
}